// Round 7
// baseline (312.472 us; speedup 1.0000x reference)
//
#include <hip/hip_runtime.h>
#include <cstdint>
#include <cstddef>

typedef unsigned short ushort_t;
typedef unsigned int uint;

typedef __attribute__((ext_vector_type(8))) short short8;   // 8 x bf16 (4 VGPRs)
typedef __attribute__((ext_vector_type(4))) float floatx4;  // 4 x f32

#define CDIM 768

// ---------- bf16 helpers (raw ushort representation) ----------
__device__ __forceinline__ float bfu(ushort_t u) {
    return __uint_as_float(((uint)u) << 16);
}
__device__ __forceinline__ void bf2(uint u, float& lo, float& hi) {
    lo = __uint_as_float(u << 16);
    hi = __uint_as_float(u & 0xffff0000u);
}
__device__ __forceinline__ ushort_t f2bfu(float f) {
    uint u = __float_as_uint(f);
    u += 0x7fffu + ((u >> 16) & 1u);   // round-to-nearest-even
    return (ushort_t)(u >> 16);
}
__device__ __forceinline__ uint pack2(float a, float b) {     // RNE pack
    return (uint)f2bfu(a) | ((uint)f2bfu(b) << 16);
}
// packed RNE f32x2 -> bf16x2 (low word = first operand), 1 VALU inst
__device__ __forceinline__ uint cvt2(float lo, float hi) {
    uint r;
    asm("v_cvt_pk_bf16_f32 %0, %1, %2" : "=v"(r) : "v"(lo), "v"(hi));
    return r;
}
__device__ __forceinline__ short8 mk8(uint a, uint b, uint c, uint d) {
    union { uint4 u; short8 s; } x;
    x.u = (uint4){a, b, c, d};
    return x.s;
}
__device__ __forceinline__ void gload_lds16(const void* g, void* l) {
    __builtin_amdgcn_global_load_lds(
        (__attribute__((address_space(1))) void*)(uintptr_t)g,
        (__attribute__((address_space(3))) void*)l, 16, 0, 0);
}

// ---------- Kernel 0a: convert Wq/Wk/Wv (fp32) -> bf16, RNE ----------
__global__ __launch_bounds__(256) void cvt_w(
    const float* __restrict__ Wq, const float* __restrict__ Wk,
    const float* __restrict__ Wv, ushort_t* __restrict__ wb)
{
    const int m = blockIdx.y;
    const float* src = (m == 0) ? Wq : (m == 1 ? Wk : Wv);
    ushort_t* dst = wb + (size_t)m * 589824;
    const int i = (blockIdx.x * 256 + threadIdx.x) * 8;
    const float4 f0 = *(const float4*)(src + i);
    const float4 f1 = *(const float4*)(src + i + 4);
    uint4 u;
    u.x = pack2(f0.x, f0.y);
    u.y = pack2(f0.z, f0.w);
    u.z = pack2(f1.x, f1.y);
    u.w = pack2(f1.z, f1.w);
    *(uint4*)(dst + i) = u;
}

// ---------- Kernel 0b: convert s1/s2 (fp32) -> bf16 activations ----------
__global__ __launch_bounds__(256) void cvt_a(
    const float* __restrict__ s1, const float* __restrict__ s2,
    ushort_t* __restrict__ ab)
{
    const int m = blockIdx.y;
    const float* src = (m == 0) ? s1 : s2;
    ushort_t* dst = ab + (size_t)m * 25165824;
    const size_t i = ((size_t)blockIdx.x * 256 + threadIdx.x) * 8;  // 12288 blocks
    const float4 f0 = *(const float4*)(src + i);
    const float4 f1 = *(const float4*)(src + i + 4);
    uint4 u;
    u.x = pack2(f0.x, f0.y);
    u.y = pack2(f0.z, f0.w);
    u.z = pack2(f1.x, f1.y);
    u.w = pack2(f1.z, f1.w);
    *(uint4*)(dst + i) = u;
}

// ---------- Kernel 0c: init agent accumulator with the q-bias ----------
__global__ __launch_bounds__(256) void init_agent(const float* __restrict__ bq,
                                                  float* __restrict__ agent)
{
    const int bh = blockIdx.x;          // 96
    const int h = bh % 12;
    for (int i = threadIdx.x; i < 1024; i += 256)
        agent[(size_t)bh * 1024 + i] = bq[h * 64 + (i & 63)];
}

// ---------- Kernel 1: fused QKV GEMM (round-0 structure: all-bf16, pure
// global_load_lds staging) + XCD swizzle + fused agent pooling ----------
// Between the two barriers: ONLY async gload_lds issues (4 A + 4 W). This is
// the only schedule measured at 161 us / MfmaUtil 30% (4 fused-A variants all
// landed at 219-250).
__global__ __launch_bounds__(256, 2) void gemm_qkv(
    const ushort_t* __restrict__ ab, const ushort_t* __restrict__ wb,
    const float* __restrict__ bq, const float* __restrict__ bk, const float* __restrict__ bv,
    ushort_t* __restrict__ qo, ushort_t* __restrict__ ko, ushort_t* __restrict__ vo,
    float* __restrict__ agent)
{
    const int z = blockIdx.z;
    const ushort_t* A     = ab + (size_t)(z != 0) * 25165824;
    const ushort_t* W     = wb + (size_t)z * 589824;
    const float* bias     = (z == 0) ? bq : (z == 1 ? bk : bv);
    ushort_t* out         = (z == 0) ? qo : (z == 1 ? ko : vo);

    __shared__ ushort_t At[128 * 64];   // 16 KB
    __shared__ ushort_t Wt[128 * 64];   // 16 KB

    const int tid  = threadIdx.x;
    const int wave = tid >> 6;
    const int lane = tid & 63;
    const int wm = wave >> 1, wn = wave & 1;

    // XCD-aware swizzle: 1536 blocks/plane, 8 XCDs, 192 blocks/chunk (bijective).
    // 6 consecutive ids share one m-panel across all 6 col-blocks -> A re-reads
    // become L2 hits on that XCD.
    const int id   = blockIdx.x + (blockIdx.y << 8);   // gridDim.x = 256
    const int id2  = (id & 7) * 192 + (id >> 3);
    const int row0 = (id2 / 6) * 128;   // token rows (b*4096+m)
    const int col0 = (id2 % 6) * 128;   // output channels

    // staging: lane j covers row_off = j>>3, source chunk = (j&7) ^ (j>>3)
    const int sro = lane >> 3;
    const int sch = ((lane & 7) ^ sro) * 8;
    const ushort_t* gaBase = A + (size_t)(row0 + wave * 32 + sro) * CDIM + sch;
    const ushort_t* gwBase = W + (size_t)(col0 + wave * 32 + sro) * CDIM + sch;

    floatx4 acc[4][4];
    #pragma unroll
    for (int i = 0; i < 4; ++i)
        #pragma unroll
        for (int j = 0; j < 4; ++j)
            acc[i][j] = (floatx4){0.f, 0.f, 0.f, 0.f};

    const int q4 = lane >> 4, r16 = lane & 15;

    for (int kt = 0; kt < CDIM; kt += 64) {
        __syncthreads();
        #pragma unroll
        for (int i = 0; i < 4; ++i) {
            gload_lds16(gaBase + (size_t)i * 8 * CDIM + kt, &At[(wave * 32 + i * 8) * 64]);
            gload_lds16(gwBase + (size_t)i * 8 * CDIM + kt, &Wt[(wave * 32 + i * 8) * 64]);
        }
        __syncthreads();
        #pragma unroll
        for (int ks = 0; ks < 2; ++ks) {
            short8 af[4], bfr[4];
            #pragma unroll
            for (int mt = 0; mt < 4; ++mt) {
                const int row = wm * 64 + mt * 16 + r16;
                const int ch  = (ks * 4 + q4) ^ (row & 7);
                af[mt] = *(const short8*)&At[row * 64 + ch * 8];
            }
            #pragma unroll
            for (int nt = 0; nt < 4; ++nt) {
                const int row = wn * 64 + nt * 16 + r16;
                const int ch  = (ks * 4 + q4) ^ (row & 7);
                bfr[nt] = *(const short8*)&Wt[row * 64 + ch * 8];
            }
            #pragma unroll
            for (int mt = 0; mt < 4; ++mt)
                #pragma unroll
                for (int nt = 0; nt < 4; ++nt)
                    acc[mt][nt] = __builtin_amdgcn_mfma_f32_16x16x32_bf16(
                        af[mt], bfr[nt], acc[mt][nt], 0, 0, 0);
        }
    }

    // epilogue: C/D layout col=lane&15, row=(lane>>4)*4+reg -> head-major store.
    // z==0 additionally folds the adaptive-avg-pool (block's 128 rows lie in one
    // agent chunk): shfl-reduce over q4 lanes, one atomicAdd per col per wave.
    const int b = row0 >> 12;
    const int m_base = row0 & 4095;
    #pragma unroll
    for (int nt = 0; nt < 4; ++nt) {
        const int col = col0 + wn * 64 + nt * 16 + r16;
        const int h = col >> 6, d = col & 63;
        const float bb = bias[col];
        ushort_t* ob = out + ((size_t)(b * 12 + h) * 4096) * 64 + d;
        float psum = 0.f;
        #pragma unroll
        for (int mt = 0; mt < 4; ++mt) {
            const int m = m_base + wm * 64 + mt * 16 + q4 * 4;
            #pragma unroll
            for (int r = 0; r < 4; ++r) {
                ob[(size_t)(m + r) * 64] = f2bfu(acc[mt][nt][r] + bb);
                psum += acc[mt][nt][r];
            }
        }
        if (z == 0) {
            psum += __shfl_xor(psum, 16);
            psum += __shfl_xor(psum, 32);
            if (q4 == 0)
                atomicAdd(&agent[(size_t)(b * 12 + h) * 1024 + (m_base >> 8) * 64 + d],
                          psum * (1.0f / 256.0f));
        }
    }
}

// ---------- Kernel 3: stage-2 agent bias ab[h][a] (fp32) ----------
__global__ void bias_ab_k(const float* __restrict__ na, const float* __restrict__ ha,
                          const float* __restrict__ wa, float* __restrict__ ab)
{
    const int t = threadIdx.x;
    if (t >= 192) return;
    const int h = t >> 4, a = t & 15;
    const float cw[7] = {2.25f, 2.34375f, 2.28125f, 2.25f, 2.28125f, 2.34375f, 2.25f};
    float acc = 0.f;
    const float* nb = na + (h * 16 + a) * 49;
    for (int i = 0; i < 7; ++i)
        for (int j = 0; j < 7; ++j)
            acc += cw[i] * cw[j] * nb[i * 7 + j];
    acc *= (1.0f / 256.0f);
    float s = 0.f;
    for (int p = 0; p < 16; ++p)
        s += ha[(h * 16 + p) * 16 + a] + wa[(h * 16 + p) * 16 + a];
    ab[t] = acc + s * (1.0f / 16.0f);
}

// ---------- Kernel 4: stage 1 (agent -> keys/values), 512 threads, 16 partials --
// Part A: each of 512 threads computes one K-row's 16 agent-dots + exp -> E2.
// Part B: threads split in two halves (half = tid>>8), each covering 256 m-rows;
// partials written at z2 = 2z + half. Doubles occupancy (12 -> 24 waves/CU) and
// halves the serial V-loop length vs the 256-thread version.
__global__ __launch_bounds__(512) void stage1(
    const ushort_t* __restrict__ k_hm, const ushort_t* __restrict__ v_hm,
    const float* __restrict__ agent, float* __restrict__ Sp, float* __restrict__ avp)
{
    const int bh = blockIdx.x, z = blockIdx.y;
    const int tid = threadIdx.x;
    __shared__ float ahs[1024];          // ah * scale, [a][d]
    __shared__ ushort_t E2[512 * 20];    // [m_local][a] bf16, row padded to 40 B

    for (int i = tid; i < 1024; i += 512)
        ahs[i] = agent[(size_t)bh * 1024 + i] * 0.125f;
    __syncthreads();

    const int m0 = z * 512;
    const ushort_t* kb = k_hm + ((size_t)bh * 4096 + m0) * 64;

    {
        const uint4* kr = (const uint4*)(kb + (size_t)tid * 64);
        uint ku[16];
        #pragma unroll
        for (int i = 0; i < 4; ++i) {
            uint4 ua = kr[i];
            ku[i*4+0] = ua.x; ku[i*4+1] = ua.y; ku[i*4+2] = ua.z; ku[i*4+3] = ua.w;
        }
        float ds[16];
        #pragma unroll
        for (int a = 0; a < 16; ++a) ds[a] = 0.f;
        #pragma unroll
        for (int c = 0; c < 16; ++c) {
            float a0, a1, a2, a3;
            bf2(ku[2*c],   a0, a1); bf2(ku[2*c+1], a2, a3);
            #pragma unroll
            for (int a = 0; a < 16; ++a) {
                const floatx4 av = *(const floatx4*)&ahs[a * 64 + c * 4];
                ds[a] += a0 * av[0] + a1 * av[1] + a2 * av[2] + a3 * av[3];
            }
        }
        uint e[8];
        #pragma unroll
        for (int a2 = 0; a2 < 8; ++a2)
            e[a2] = pack2(__expf(ds[2*a2]), __expf(ds[2*a2+1]));
        uint2* dA = (uint2*)&E2[(size_t)tid * 20];
        dA[0] = make_uint2(e[0], e[1]); dA[1] = make_uint2(e[2], e[3]);
        dA[2] = make_uint2(e[4], e[5]); dA[3] = make_uint2(e[6], e[7]);
    }
    __syncthreads();

    const int d = tid & 63, g = (tid >> 6) & 3, half = tid >> 8;
    const int mb = half * 256;
    const ushort_t* vb = v_hm + ((size_t)bh * 4096 + m0 + mb) * 64 + d;
    float acc0 = 0, acc1 = 0, acc2 = 0, acc3 = 0;
    float ss0 = 0, ss1 = 0, ss2 = 0, ss3 = 0;
    for (int ml = 0; ml < 256; ++ml) {
        const float vv = bfu(vb[(size_t)ml * 64]);
        const uint2 ee = *(const uint2*)&E2[(size_t)(mb + ml) * 20 + g * 4];
        float e0, e1, e2, e3;
        bf2(ee.x, e0, e1);
        bf2(ee.y, e2, e3);
        acc0 += e0 * vv; ss0 += e0;
        acc1 += e1 * vv; ss1 += e1;
        acc2 += e2 * vv; ss2 += e2;
        acc3 += e3 * vv; ss3 += e3;
    }
    const int z2 = z * 2 + half;
    float* avz = avp + (size_t)(z2 * 96 + bh) * 1024;
    avz[(g * 4 + 0) * 64 + d] = acc0;
    avz[(g * 4 + 1) * 64 + d] = acc1;
    avz[(g * 4 + 2) * 64 + d] = acc2;
    avz[(g * 4 + 3) * 64 + d] = acc3;
    if (d == 0) {
        float* Sz = Sp + (z2 * 96 + bh) * 16;
        Sz[g * 4 + 0] = ss0;
        Sz[g * 4 + 1] = ss1;
        Sz[g * 4 + 2] = ss2;
        Sz[g * 4 + 3] = ss3;
    }
}

// ---------- Kernel 5: stage 2 (queries -> agents) via MFMA ----------
// Swapped-operand scheme (verified round 5). 16 partials now.
__global__ __launch_bounds__(256) void stage2(
    const ushort_t* __restrict__ q_hm, const float* __restrict__ avp,
    const float* __restrict__ Sp, const float* __restrict__ agent,
    const float* __restrict__ ab, float* __restrict__ out)
{
    const int nb = blockIdx.x;           // 16
    const int bh = blockIdx.y;           // 96
    const int b = bh / 12, h = bh % 12;
    const int tid = threadIdx.x;
    const int g = (tid >> 4) & 3;        // lane>>4 (quad group)
    const int t = tid & 15;              // lane&15
    const int w = tid >> 6;              // wave
    __shared__ float avn[1024];          // normalized agent_v, [a][d] fp32

    // avn = (sum_z2 avp) / (sum_z2 Sp)
    {
        const int i4 = tid * 4;
        const int a = i4 >> 6;
        floatx4 num = {0.f, 0.f, 0.f, 0.f};
        float den = 0.f;
        #pragma unroll
        for (int zz = 0; zz < 16; ++zz) {
            num += *(const floatx4*)&avp[(size_t)(zz * 96 + bh) * 1024 + i4];
            den += Sp[(zz * 96 + bh) * 16 + a];
        }
        const float r = 1.0f / den;
        *(floatx4*)&avn[i4] = num * r;
    }
    __syncthreads();

    // ah A-fragments (value + residual): lane holds ah[t][k0*32 + g*8 + j]*scale
    short8 ahA[2], ahE[2];
    #pragma unroll
    for (int k0 = 0; k0 < 2; ++k0) {
        const float* p = agent + (size_t)bh * 1024 + t * 64 + k0 * 32 + g * 8;
        const float4 f0 = *(const float4*)p;
        const float4 f1 = *(const float4*)(p + 4);
        const float v[8] = {f0.x, f0.y, f0.z, f0.w, f1.x, f1.y, f1.z, f1.w};
        uint u[4], e[4];
        #pragma unroll
        for (int j = 0; j < 4; ++j) {
            const float a0 = v[2*j] * 0.125f, a1 = v[2*j+1] * 0.125f;
            u[j] = cvt2(a0, a1);
            float b0, b1; bf2(u[j], b0, b1);
            e[j] = cvt2(a0 - b0, a1 - b1);
        }
        ahA[k0] = mk8(u[0], u[1], u[2], u[3]);
        ahE[k0] = mk8(e[0], e[1], e[2], e[3]);
    }

    // av^T A-fragments (value + residual): lane holds avn[8g+j][dt*16 + t]; g>=2 zero
    short8 avf[4], ave[4];
    #pragma unroll
    for (int dt = 0; dt < 4; ++dt) {
        uint u[4] = {0, 0, 0, 0}, e[4] = {0, 0, 0, 0};
        if (g < 2) {
            #pragma unroll
            for (int j = 0; j < 4; ++j) {
                const float a0 = avn[(8*g + 2*j)     * 64 + dt * 16 + t];
                const float a1 = avn[(8*g + 2*j + 1) * 64 + dt * 16 + t];
                u[j] = cvt2(a0, a1);
                float b0, b1; bf2(u[j], b0, b1);
                e[j] = cvt2(a0 - b0, a1 - b1);
            }
        }
        avf[dt] = mk8(u[0], u[1], u[2], u[3]);
        ave[dt] = mk8(e[0], e[1], e[2], e[3]);
    }

    float abv[4];
    #pragma unroll
    for (int r = 0; r < 4; ++r) abv[r] = ab[h * 16 + 4 * g + r];

    const int src0 = (t + 32 * g) & 63;
    const int src1 = (src0 + 16) & 63;
    const int n0 = nb * 256 + w * 64;
    const ushort_t* qb = q_hm + ((size_t)bh * 4096 + n0) * 64;
    float* ob = out + ((size_t)b * 4096 + n0) * CDIM + h * 64;

    #pragma unroll
    for (int ti = 0; ti < 4; ++ti) {
        // Q B-fragments: lane holds Q[ti*16+t][k0*32 + g*8 + j]
        const ushort_t* qp = qb + (size_t)(ti * 16 + t) * 64 + g * 8;
        const short8 qB0 = *(const short8*)(qp);
        const short8 qB1 = *(const short8*)(qp + 32);

        floatx4 sc = {0.f, 0.f, 0.f, 0.f};
        sc = __builtin_amdgcn_mfma_f32_16x16x32_bf16(ahA[0], qB0, sc, 0, 0, 0);
        sc = __builtin_amdgcn_mfma_f32_16x16x32_bf16(ahA[1], qB1, sc, 0, 0, 0);
        sc = __builtin_amdgcn_mfma_f32_16x16x32_bf16(ahE[0], qB0, sc, 0, 0, 0);
        sc = __builtin_amdgcn_mfma_f32_16x16x32_bf16(ahE[1], qB1, sc, 0, 0, 0);

        // softmax over agents (rows): in-lane + cross-group
        const float e0 = __expf(sc[0] + abv[0]);
        const float e1 = __expf(sc[1] + abv[1]);
        const float e2 = __expf(sc[2] + abv[2]);
        const float e3 = __expf(sc[3] + abv[3]);
        float s = e0 + e1 + e2 + e3;
        s += __shfl_xor(s, 16);
        s += __shfl_xor(s, 32);
        const float rs = 1.0f / s;
        const float p0 = e0 * rs, p1 = e1 * rs, p2 = e2 * rs, p3 = e3 * rs;

        // pack own P (agents 4g..4g+3, token t) + residual
        const uint P0 = cvt2(p0, p1), P1 = cvt2(p2, p3);
        float q0, q1, q2, q3;
        bf2(P0, q0, q1); bf2(P1, q2, q3);
        const uint E0 = cvt2(p0 - q0, p1 - q1), E1 = cvt2(p2 - q2, p3 - q3);

        // regroup into K=32-padded B-fragment: k=8g+j -> agents from groups 2g, 2g+1
        uint w0 = __shfl(P0, src0), w1 = __shfl(P1, src0);
        uint w2 = __shfl(P0, src1), w3 = __shfl(P1, src1);
        uint x0 = __shfl(E0, src0), x1 = __shfl(E1, src0);
        uint x2 = __shfl(E0, src1), x3 = __shfl(E1, src1);
        if (g >= 2) { w0 = w1 = w2 = w3 = 0; x0 = x1 = x2 = x3 = 0; }
        const short8 pf = mk8(w0, w1, w2, w3);
        const short8 pe = mk8(x0, x1, x2, x3);

        // PV: out^T[dt*16 + 4g + r][t], residual-corrected
        float* op = ob + (size_t)(ti * 16 + t) * CDIM + 4 * g;
        #pragma unroll
        for (int dt = 0; dt < 4; ++dt) {
            floatx4 od = {0.f, 0.f, 0.f, 0.f};
            od = __builtin_amdgcn_mfma_f32_16x16x32_bf16(avf[dt], pf, od, 0, 0, 0);
            od = __builtin_amdgcn_mfma_f32_16x16x32_bf16(avf[dt], pe, od, 0, 0, 0);
            od = __builtin_amdgcn_mfma_f32_16x16x32_bf16(ave[dt], pf, od, 0, 0, 0);
            *(floatx4*)(op + dt * 16) = od;
        }
    }
}

// ---------- launcher ----------
extern "C" void kernel_launch(void* const* d_in, const int* in_sizes, int n_in,
                              void* d_out, int out_size, void* d_ws, size_t ws_size,
                              hipStream_t stream) {
    (void)in_sizes; (void)n_in; (void)out_size; (void)ws_size;
    const float* s1 = (const float*)d_in[0];
    const float* s2 = (const float*)d_in[1];
    const float* Wq = (const float*)d_in[2];
    const float* bq = (const float*)d_in[3];
    const float* Wk = (const float*)d_in[4];
    const float* bk = (const float*)d_in[5];
    const float* Wv = (const float*)d_in[6];
    const float* bv = (const float*)d_in[7];
    const float* na = (const float*)d_in[9];
    const float* ha = (const float*)d_in[12];
    const float* wa = (const float*)d_in[13];
    float* out = (float*)d_out;

    char* ws = (char*)d_ws;
    ushort_t* q_hm = (ushort_t*)(ws);                 // 50,331,648 B  [96][4096][64]
    ushort_t* k_hm = (ushort_t*)(ws + 50331648);      // 50,331,648 B
    ushort_t* v_hm = (ushort_t*)(ws + 100663296);     // 50,331,648 B
    float* agent   = (float*)(ws + 150994944);        //    393,216 B  [96][16][64]
    float* Sp      = (float*)(ws + 151388160);        //     98,304 B  [16][96][16]
    float* ab      = (float*)(ws + 151486464);        //        768 B
    ushort_t* wb   = (ushort_t*)(ws + 151487232);     //  3,538,944 B  [3][768][768]
    ushort_t* abuf = (ushort_t*)(ws + 155026176);     // 100,663,296 B [2][32768][768]  (live cvt_a..gemm)
    float* avp     = (float*)(ws + 155026176);        //  6,291,456 B  [16][96][16][64] (live stage1..stage2, overlays dead abuf)

    cvt_w      <<<dim3(288, 3),    256, 0, stream>>>(Wq, Wk, Wv, wb);
    cvt_a      <<<dim3(12288, 2),  256, 0, stream>>>(s1, s2, abuf);
    init_agent <<<dim3(96),        256, 0, stream>>>(bq, agent);
    gemm_qkv   <<<dim3(256, 6, 3), 256, 0, stream>>>(abuf, wb, bq, bk, bv,
                                                     q_hm, k_hm, v_hm, agent);
    bias_ab_k  <<<1, 256, 0, stream>>>(na, ha, wa, ab);
    stage1     <<<dim3(96, 8),     512, 0, stream>>>(k_hm, v_hm, agent, Sp, avp);
    stage2     <<<dim3(16, 96),    256, 0, stream>>>(q_hm, avp, Sp, agent, ab, out);
}

// Round 8
// 295.775 us; speedup vs baseline: 1.0565x; 1.0565x over previous
//
#include <hip/hip_runtime.h>
#include <cstdint>
#include <cstddef>

typedef unsigned short ushort_t;
typedef unsigned int uint;

typedef __attribute__((ext_vector_type(8))) short short8;   // 8 x bf16 (4 VGPRs)
typedef __attribute__((ext_vector_type(4))) float floatx4;  // 4 x f32

#define CDIM 768

// ---------- bf16 helpers (raw ushort representation) ----------
__device__ __forceinline__ float bfu(ushort_t u) {
    return __uint_as_float(((uint)u) << 16);
}
__device__ __forceinline__ void bf2(uint u, float& lo, float& hi) {
    lo = __uint_as_float(u << 16);
    hi = __uint_as_float(u & 0xffff0000u);
}
__device__ __forceinline__ ushort_t f2bfu(float f) {
    uint u = __float_as_uint(f);
    u += 0x7fffu + ((u >> 16) & 1u);   // round-to-nearest-even
    return (ushort_t)(u >> 16);
}
__device__ __forceinline__ uint pack2(float a, float b) {     // RNE pack
    return (uint)f2bfu(a) | ((uint)f2bfu(b) << 16);
}
// packed RNE f32x2 -> bf16x2 (low word = first operand), 1 VALU inst
__device__ __forceinline__ uint cvt2(float lo, float hi) {
    uint r;
    asm("v_cvt_pk_bf16_f32 %0, %1, %2" : "=v"(r) : "v"(lo), "v"(hi));
    return r;
}
__device__ __forceinline__ short8 mk8(uint a, uint b, uint c, uint d) {
    union { uint4 u; short8 s; } x;
    x.u = (uint4){a, b, c, d};
    return x.s;
}
__device__ __forceinline__ void gload_lds16(const void* g, void* l) {
    __builtin_amdgcn_global_load_lds(
        (__attribute__((address_space(1))) void*)(uintptr_t)g,
        (__attribute__((address_space(3))) void*)l, 16, 0, 0);
}

// ---------- Kernel 0a: prep = cvt_w (864 blocks) + init_agent (96) + bias_ab (1) --
__global__ __launch_bounds__(256) void prep(
    const float* __restrict__ Wq, const float* __restrict__ Wk,
    const float* __restrict__ Wv, const float* __restrict__ bq,
    const float* __restrict__ na, const float* __restrict__ ha,
    const float* __restrict__ wa,
    ushort_t* __restrict__ wb, float* __restrict__ agent, float* __restrict__ ab)
{
    const int bid = blockIdx.x;
    if (bid < 864) {
        // cvt Wq/Wk/Wv (fp32) -> bf16 RNE
        const int m = bid / 288;
        const float* src = (m == 0) ? Wq : (m == 1 ? Wk : Wv);
        ushort_t* dst = wb + (size_t)m * 589824;
        const int i = ((bid % 288) * 256 + threadIdx.x) * 8;
        const float4 f0 = *(const float4*)(src + i);
        const float4 f1 = *(const float4*)(src + i + 4);
        uint4 u;
        u.x = pack2(f0.x, f0.y);
        u.y = pack2(f0.z, f0.w);
        u.z = pack2(f1.x, f1.y);
        u.w = pack2(f1.z, f1.w);
        *(uint4*)(dst + i) = u;
    } else if (bid < 960) {
        // init agent accumulator with the q-bias
        const int bh = bid - 864;
        const int h = bh % 12;
        for (int i = threadIdx.x; i < 1024; i += 256)
            agent[(size_t)bh * 1024 + i] = bq[h * 64 + (i & 63)];
    } else {
        // stage-2 agent bias ab[h][a]
        const int t = threadIdx.x;
        if (t >= 192) return;
        const int h = t >> 4, a = t & 15;
        const float cw[7] = {2.25f, 2.34375f, 2.28125f, 2.25f, 2.28125f, 2.34375f, 2.25f};
        float acc = 0.f;
        const float* nb = na + (h * 16 + a) * 49;
        for (int i = 0; i < 7; ++i)
            for (int j = 0; j < 7; ++j)
                acc += cw[i] * cw[j] * nb[i * 7 + j];
        acc *= (1.0f / 256.0f);
        float s = 0.f;
        for (int p = 0; p < 16; ++p)
            s += ha[(h * 16 + p) * 16 + a] + wa[(h * 16 + p) * 16 + a];
        ab[t] = acc + s * (1.0f / 16.0f);
    }
}

// ---------- Kernel 0b: convert s1/s2 (fp32) -> bf16 activations ----------
__global__ __launch_bounds__(256) void cvt_a(
    const float* __restrict__ s1, const float* __restrict__ s2,
    ushort_t* __restrict__ ab)
{
    const int m = blockIdx.y;
    const float* src = (m == 0) ? s1 : s2;
    ushort_t* dst = ab + (size_t)m * 25165824;
    const size_t i = ((size_t)blockIdx.x * 256 + threadIdx.x) * 8;  // 12288 blocks
    const float4 f0 = *(const float4*)(src + i);
    const float4 f1 = *(const float4*)(src + i + 4);
    uint4 u;
    u.x = pack2(f0.x, f0.y);
    u.y = pack2(f0.z, f0.w);
    u.z = pack2(f1.x, f1.y);
    u.w = pack2(f1.z, f1.w);
    *(uint4*)(dst + i) = u;
}

// ---------- Kernel 1: fused QKV GEMM (round-0 structure: all-bf16, pure
// global_load_lds staging) + XCD swizzle + fused agent pooling + LDS-staged
// coalesced epilogue ----------
// Between the two barriers: ONLY async gload_lds issues (4 A + 4 W) — the only
// schedule measured at ~155 us / MfmaUtil 33 (4 fused-A variants: 219-250).
// Epilogue: stage bf16(acc+bias) in LDS [128][136], then full 128-B-row uint4
// stores (replaces 64 scalar shorts/thread; WRITE_SIZE 233 -> ~155 MB).
__global__ __launch_bounds__(256, 2) void gemm_qkv(
    const ushort_t* __restrict__ ab, const ushort_t* __restrict__ wb,
    const float* __restrict__ bq, const float* __restrict__ bk, const float* __restrict__ bv,
    ushort_t* __restrict__ qo, ushort_t* __restrict__ ko, ushort_t* __restrict__ vo,
    float* __restrict__ agent)
{
    const int z = blockIdx.z;
    const ushort_t* A     = ab + (size_t)(z != 0) * 25165824;
    const ushort_t* W     = wb + (size_t)z * 589824;
    const float* bias     = (z == 0) ? bq : (z == 1 ? bk : bv);
    ushort_t* out         = (z == 0) ? qo : (z == 1 ? ko : vo);

    __shared__ ushort_t lds[17408];     // 34,816 B: At=[0:8192], Wt=[8192:16384];
    ushort_t* At = lds;                 // epilogue reuses all as [128][136]
    ushort_t* Wt = lds + 8192;

    const int tid  = threadIdx.x;
    const int wave = tid >> 6;
    const int lane = tid & 63;
    const int wm = wave >> 1, wn = wave & 1;

    // XCD-aware swizzle: 1536 blocks/plane, 8 XCDs, 192 blocks/chunk (bijective).
    const int id   = blockIdx.x + (blockIdx.y << 8);   // gridDim.x = 256
    const int id2  = (id & 7) * 192 + (id >> 3);
    const int row0 = (id2 / 6) * 128;   // token rows (b*4096+m)
    const int col0 = (id2 % 6) * 128;   // output channels

    // staging: lane j covers row_off = j>>3, source chunk = (j&7) ^ (j>>3)
    const int sro = lane >> 3;
    const int sch = ((lane & 7) ^ sro) * 8;
    const ushort_t* gaBase = A + (size_t)(row0 + wave * 32 + sro) * CDIM + sch;
    const ushort_t* gwBase = W + (size_t)(col0 + wave * 32 + sro) * CDIM + sch;

    floatx4 acc[4][4];
    #pragma unroll
    for (int i = 0; i < 4; ++i)
        #pragma unroll
        for (int j = 0; j < 4; ++j)
            acc[i][j] = (floatx4){0.f, 0.f, 0.f, 0.f};

    const int q4 = lane >> 4, r16 = lane & 15;

    for (int kt = 0; kt < CDIM; kt += 64) {
        __syncthreads();
        #pragma unroll
        for (int i = 0; i < 4; ++i) {
            gload_lds16(gaBase + (size_t)i * 8 * CDIM + kt, &At[(wave * 32 + i * 8) * 64]);
            gload_lds16(gwBase + (size_t)i * 8 * CDIM + kt, &Wt[(wave * 32 + i * 8) * 64]);
        }
        __syncthreads();
        #pragma unroll
        for (int ks = 0; ks < 2; ++ks) {
            short8 af[4], bfr[4];
            #pragma unroll
            for (int mt = 0; mt < 4; ++mt) {
                const int row = wm * 64 + mt * 16 + r16;
                const int ch  = (ks * 4 + q4) ^ (row & 7);
                af[mt] = *(const short8*)&At[row * 64 + ch * 8];
            }
            #pragma unroll
            for (int nt = 0; nt < 4; ++nt) {
                const int row = wn * 64 + nt * 16 + r16;
                const int ch  = (ks * 4 + q4) ^ (row & 7);
                bfr[nt] = *(const short8*)&Wt[row * 64 + ch * 8];
            }
            #pragma unroll
            for (int mt = 0; mt < 4; ++mt)
                #pragma unroll
                for (int nt = 0; nt < 4; ++nt)
                    acc[mt][nt] = __builtin_amdgcn_mfma_f32_16x16x32_bf16(
                        af[mt], bfr[nt], acc[mt][nt], 0, 0, 0);
        }
    }

    // ---- epilogue v2: LDS-staged coalesced store ----
    // C/D layout: col = lane&15 (r16), row = q4*4 + r. Stage bf16(acc+bias) into
    // lds[row_local][136], pool (z==0) on raw acc, then write full 128-B rows.
    __syncthreads();    // all LDS reads of the last K-tile complete
    const int b = row0 >> 12;
    const int m_base = row0 & 4095;
    #pragma unroll
    for (int nt = 0; nt < 4; ++nt) {
        const int coll = wn * 64 + nt * 16 + r16;     // col-local 0..127
        const float bb = bias[col0 + coll];
        float psum = 0.f;
        #pragma unroll
        for (int mt = 0; mt < 4; ++mt) {
            const int rowl = wm * 64 + mt * 16 + q4 * 4;
            #pragma unroll
            for (int r = 0; r < 4; ++r) {
                lds[(rowl + r) * 136 + coll] = f2bfu(acc[mt][nt][r] + bb);
                psum += acc[mt][nt][r];
            }
        }
        if (z == 0) {
            psum += __shfl_xor(psum, 16);
            psum += __shfl_xor(psum, 32);
            if (q4 == 0) {
                const int h = (col0 + coll) >> 6, d = (col0 + coll) & 63;
                atomicAdd(&agent[(size_t)(b * 12 + h) * 1024 + (m_base >> 8) * 64 + d],
                          psum * (1.0f / 256.0f));
            }
        }
    }
    __syncthreads();
    // 256 rows (128 m x 2 heads) x 128 B; 8 lanes per row, uint4 each.
    #pragma unroll
    for (int it = 0; it < 8; ++it) {
        const int task  = it * 256 + tid;
        const int chunk = task & 7;          // 16-B chunk within the row
        const int rh    = task >> 3;         // 0..255
        const int rowl  = rh >> 1, hl = rh & 1;
        const uint4 v = *(const uint4*)&lds[rowl * 136 + hl * 64 + chunk * 8];
        ushort_t* op = out + ((size_t)(b * 12 + (col0 >> 6) + hl) * 4096
                              + m_base + rowl) * 64 + chunk * 8;
        *(uint4*)op = v;
    }
}

// ---------- Kernel 4: stage 1 (agent -> keys/values), 512 threads, 16 partials --
// Part A: each thread computes one K-row's 16 agent-dots (FULL 64 dims — fixed
// the inherited half-row load: ku[32], 8 x uint4) + exp -> E2.
// Part B: two halves (half = tid>>8) each cover 256 m-rows; partials at
// z2 = 2z + half.
__global__ __launch_bounds__(512) void stage1(
    const ushort_t* __restrict__ k_hm, const ushort_t* __restrict__ v_hm,
    const float* __restrict__ agent, float* __restrict__ Sp, float* __restrict__ avp)
{
    const int bh = blockIdx.x, z = blockIdx.y;
    const int tid = threadIdx.x;
    __shared__ float ahs[1024];          // ah * scale, [a][d]
    __shared__ ushort_t E2[512 * 20];    // [m_local][a] bf16, row padded to 40 B

    for (int i = tid; i < 1024; i += 512)
        ahs[i] = agent[(size_t)bh * 1024 + i] * 0.125f;
    __syncthreads();

    const int m0 = z * 512;
    const ushort_t* kb = k_hm + ((size_t)bh * 4096 + m0) * 64;

    {
        const uint4* kr = (const uint4*)(kb + (size_t)tid * 64);
        uint ku[32];
        #pragma unroll
        for (int i = 0; i < 8; ++i) {
            uint4 ua = kr[i];
            ku[i*4+0] = ua.x; ku[i*4+1] = ua.y; ku[i*4+2] = ua.z; ku[i*4+3] = ua.w;
        }
        float ds[16];
        #pragma unroll
        for (int a = 0; a < 16; ++a) ds[a] = 0.f;
        #pragma unroll
        for (int c = 0; c < 16; ++c) {
            float a0, a1, a2, a3;
            bf2(ku[2*c],   a0, a1); bf2(ku[2*c+1], a2, a3);
            #pragma unroll
            for (int a = 0; a < 16; ++a) {
                const floatx4 av = *(const floatx4*)&ahs[a * 64 + c * 4];
                ds[a] += a0 * av[0] + a1 * av[1] + a2 * av[2] + a3 * av[3];
            }
        }
        uint e[8];
        #pragma unroll
        for (int a2 = 0; a2 < 8; ++a2)
            e[a2] = pack2(__expf(ds[2*a2]), __expf(ds[2*a2+1]));
        uint2* dA = (uint2*)&E2[(size_t)tid * 20];
        dA[0] = make_uint2(e[0], e[1]); dA[1] = make_uint2(e[2], e[3]);
        dA[2] = make_uint2(e[4], e[5]); dA[3] = make_uint2(e[6], e[7]);
    }
    __syncthreads();

    const int d = tid & 63, g = (tid >> 6) & 3, half = tid >> 8;
    const int mb = half * 256;
    const ushort_t* vb = v_hm + ((size_t)bh * 4096 + m0 + mb) * 64 + d;
    float acc0 = 0, acc1 = 0, acc2 = 0, acc3 = 0;
    float ss0 = 0, ss1 = 0, ss2 = 0, ss3 = 0;
    for (int ml = 0; ml < 256; ++ml) {
        const float vv = bfu(vb[(size_t)ml * 64]);
        const uint2 ee = *(const uint2*)&E2[(size_t)(mb + ml) * 20 + g * 4];
        float e0, e1, e2, e3;
        bf2(ee.x, e0, e1);
        bf2(ee.y, e2, e3);
        acc0 += e0 * vv; ss0 += e0;
        acc1 += e1 * vv; ss1 += e1;
        acc2 += e2 * vv; ss2 += e2;
        acc3 += e3 * vv; ss3 += e3;
    }
    const int z2 = z * 2 + half;
    float* avz = avp + (size_t)(z2 * 96 + bh) * 1024;
    avz[(g * 4 + 0) * 64 + d] = acc0;
    avz[(g * 4 + 1) * 64 + d] = acc1;
    avz[(g * 4 + 2) * 64 + d] = acc2;
    avz[(g * 4 + 3) * 64 + d] = acc3;
    if (d == 0) {
        float* Sz = Sp + (z2 * 96 + bh) * 16;
        Sz[g * 4 + 0] = ss0;
        Sz[g * 4 + 1] = ss1;
        Sz[g * 4 + 2] = ss2;
        Sz[g * 4 + 3] = ss3;
    }
}

// ---------- Kernel 5: stage 2 (queries -> agents) via MFMA ----------
// Swapped-operand scheme (verified round 5). 16 partials.
__global__ __launch_bounds__(256) void stage2(
    const ushort_t* __restrict__ q_hm, const float* __restrict__ avp,
    const float* __restrict__ Sp, const float* __restrict__ agent,
    const float* __restrict__ ab, float* __restrict__ out)
{
    const int nb = blockIdx.x;           // 16
    const int bh = blockIdx.y;           // 96
    const int b = bh / 12, h = bh % 12;
    const int tid = threadIdx.x;
    const int g = (tid >> 4) & 3;        // lane>>4 (quad group)
    const int t = tid & 15;              // lane&15
    const int w = tid >> 6;              // wave
    __shared__ float avn[1024];          // normalized agent_v, [a][d] fp32

    // avn = (sum_z2 avp) / (sum_z2 Sp)
    {
        const int i4 = tid * 4;
        const int a = i4 >> 6;
        floatx4 num = {0.f, 0.f, 0.f, 0.f};
        float den = 0.f;
        #pragma unroll
        for (int zz = 0; zz < 16; ++zz) {
            num += *(const floatx4*)&avp[(size_t)(zz * 96 + bh) * 1024 + i4];
            den += Sp[(zz * 96 + bh) * 16 + a];
        }
        const float r = 1.0f / den;
        *(floatx4*)&avn[i4] = num * r;
    }
    __syncthreads();

    // ah A-fragments (value + residual): lane holds ah[t][k0*32 + g*8 + j]*scale
    short8 ahA[2], ahE[2];
    #pragma unroll
    for (int k0 = 0; k0 < 2; ++k0) {
        const float* p = agent + (size_t)bh * 1024 + t * 64 + k0 * 32 + g * 8;
        const float4 f0 = *(const float4*)p;
        const float4 f1 = *(const float4*)(p + 4);
        const float v[8] = {f0.x, f0.y, f0.z, f0.w, f1.x, f1.y, f1.z, f1.w};
        uint u[4], e[4];
        #pragma unroll
        for (int j = 0; j < 4; ++j) {
            const float a0 = v[2*j] * 0.125f, a1 = v[2*j+1] * 0.125f;
            u[j] = cvt2(a0, a1);
            float b0, b1; bf2(u[j], b0, b1);
            e[j] = cvt2(a0 - b0, a1 - b1);
        }
        ahA[k0] = mk8(u[0], u[1], u[2], u[3]);
        ahE[k0] = mk8(e[0], e[1], e[2], e[3]);
    }

    // av^T A-fragments (value + residual): lane holds avn[8g+j][dt*16 + t]; g>=2 zero
    short8 avf[4], ave[4];
    #pragma unroll
    for (int dt = 0; dt < 4; ++dt) {
        uint u[4] = {0, 0, 0, 0}, e[4] = {0, 0, 0, 0};
        if (g < 2) {
            #pragma unroll
            for (int j = 0; j < 4; ++j) {
                const float a0 = avn[(8*g + 2*j)     * 64 + dt * 16 + t];
                const float a1 = avn[(8*g + 2*j + 1) * 64 + dt * 16 + t];
                u[j] = cvt2(a0, a1);
                float b0, b1; bf2(u[j], b0, b1);
                e[j] = cvt2(a0 - b0, a1 - b1);
            }
        }
        avf[dt] = mk8(u[0], u[1], u[2], u[3]);
        ave[dt] = mk8(e[0], e[1], e[2], e[3]);
    }

    float abv[4];
    #pragma unroll
    for (int r = 0; r < 4; ++r) abv[r] = ab[h * 16 + 4 * g + r];

    const int src0 = (t + 32 * g) & 63;
    const int src1 = (src0 + 16) & 63;
    const int n0 = nb * 256 + w * 64;
    const ushort_t* qb = q_hm + ((size_t)bh * 4096 + n0) * 64;
    float* ob = out + ((size_t)b * 4096 + n0) * CDIM + h * 64;

    #pragma unroll
    for (int ti = 0; ti < 4; ++ti) {
        // Q B-fragments: lane holds Q[ti*16+t][k0*32 + g*8 + j]
        const ushort_t* qp = qb + (size_t)(ti * 16 + t) * 64 + g * 8;
        const short8 qB0 = *(const short8*)(qp);
        const short8 qB1 = *(const short8*)(qp + 32);

        floatx4 sc = {0.f, 0.f, 0.f, 0.f};
        sc = __builtin_amdgcn_mfma_f32_16x16x32_bf16(ahA[0], qB0, sc, 0, 0, 0);
        sc = __builtin_amdgcn_mfma_f32_16x16x32_bf16(ahA[1], qB1, sc, 0, 0, 0);
        sc = __builtin_amdgcn_mfma_f32_16x16x32_bf16(ahE[0], qB0, sc, 0, 0, 0);
        sc = __builtin_amdgcn_mfma_f32_16x16x32_bf16(ahE[1], qB1, sc, 0, 0, 0);

        // softmax over agents (rows): in-lane + cross-group
        const float e0 = __expf(sc[0] + abv[0]);
        const float e1 = __expf(sc[1] + abv[1]);
        const float e2 = __expf(sc[2] + abv[2]);
        const float e3 = __expf(sc[3] + abv[3]);
        float s = e0 + e1 + e2 + e3;
        s += __shfl_xor(s, 16);
        s += __shfl_xor(s, 32);
        const float rs = 1.0f / s;
        const float p0 = e0 * rs, p1 = e1 * rs, p2 = e2 * rs, p3 = e3 * rs;

        // pack own P (agents 4g..4g+3, token t) + residual
        const uint P0 = cvt2(p0, p1), P1 = cvt2(p2, p3);
        float q0, q1, q2, q3;
        bf2(P0, q0, q1); bf2(P1, q2, q3);
        const uint E0 = cvt2(p0 - q0, p1 - q1), E1 = cvt2(p2 - q2, p3 - q3);

        // regroup into K=32-padded B-fragment: k=8g+j -> agents from groups 2g, 2g+1
        uint w0 = __shfl(P0, src0), w1 = __shfl(P1, src0);
        uint w2 = __shfl(P0, src1), w3 = __shfl(P1, src1);
        uint x0 = __shfl(E0, src0), x1 = __shfl(E1, src0);
        uint x2 = __shfl(E0, src1), x3 = __shfl(E1, src1);
        if (g >= 2) { w0 = w1 = w2 = w3 = 0; x0 = x1 = x2 = x3 = 0; }
        const short8 pf = mk8(w0, w1, w2, w3);
        const short8 pe = mk8(x0, x1, x2, x3);

        // PV: out^T[dt*16 + 4g + r][t], residual-corrected
        float* op = ob + (size_t)(ti * 16 + t) * CDIM + 4 * g;
        #pragma unroll
        for (int dt = 0; dt < 4; ++dt) {
            floatx4 od = {0.f, 0.f, 0.f, 0.f};
            od = __builtin_amdgcn_mfma_f32_16x16x32_bf16(avf[dt], pf, od, 0, 0, 0);
            od = __builtin_amdgcn_mfma_f32_16x16x32_bf16(avf[dt], pe, od, 0, 0, 0);
            od = __builtin_amdgcn_mfma_f32_16x16x32_bf16(ave[dt], pf, od, 0, 0, 0);
            *(floatx4*)(op + dt * 16) = od;
        }
    }
}

// ---------- launcher ----------
extern "C" void kernel_launch(void* const* d_in, const int* in_sizes, int n_in,
                              void* d_out, int out_size, void* d_ws, size_t ws_size,
                              hipStream_t stream) {
    (void)in_sizes; (void)n_in; (void)out_size; (void)ws_size;
    const float* s1 = (const float*)d_in[0];
    const float* s2 = (const float*)d_in[1];
    const float* Wq = (const float*)d_in[2];
    const float* bq = (const float*)d_in[3];
    const float* Wk = (const float*)d_in[4];
    const float* bk = (const float*)d_in[5];
    const float* Wv = (const float*)d_in[6];
    const float* bv = (const float*)d_in[7];
    const float* na = (const float*)d_in[9];
    const float* ha = (const float*)d_in[12];
    const float* wa = (const float*)d_in[13];
    float* out = (float*)d_out;

    char* ws = (char*)d_ws;
    ushort_t* q_hm = (ushort_t*)(ws);                 // 50,331,648 B  [96][4096][64]
    ushort_t* k_hm = (ushort_t*)(ws + 50331648);      // 50,331,648 B
    ushort_t* v_hm = (ushort_t*)(ws + 100663296);     // 50,331,648 B
    float* agent   = (float*)(ws + 150994944);        //    393,216 B  [96][16][64]
    float* Sp      = (float*)(ws + 151388160);        //     98,304 B  [16][96][16]
    float* ab      = (float*)(ws + 151486464);        //        768 B
    ushort_t* wb   = (ushort_t*)(ws + 151487232);     //  3,538,944 B  [3][768][768]
    ushort_t* abuf = (ushort_t*)(ws + 155026176);     // 100,663,296 B [2][32768][768]  (live cvt_a..gemm)
    float* avp     = (float*)(ws + 155026176);        //  6,291,456 B  [16][96][16][64] (live stage1..stage2, overlays dead abuf)

    prep     <<<dim3(961),       256, 0, stream>>>(Wq, Wk, Wv, bq, na, ha, wa,
                                                   wb, agent, ab);
    cvt_a    <<<dim3(12288, 2),  256, 0, stream>>>(s1, s2, abuf);
    gemm_qkv <<<dim3(256, 6, 3), 256, 0, stream>>>(abuf, wb, bq, bk, bv,
                                                   q_hm, k_hm, v_hm, agent);
    stage1   <<<dim3(96, 8),     512, 0, stream>>>(k_hm, v_hm, agent, Sp, avp);
    stage2   <<<dim3(16, 96),    256, 0, stream>>>(q_hm, avp, Sp, agent, ab, out);
}

// Round 9
// 278.270 us; speedup vs baseline: 1.1229x; 1.0629x over previous
//
#include <hip/hip_runtime.h>
#include <cstdint>
#include <cstddef>

typedef unsigned short ushort_t;
typedef unsigned int uint;

typedef __attribute__((ext_vector_type(8))) short short8;   // 8 x bf16 (4 VGPRs)
typedef __attribute__((ext_vector_type(4))) float floatx4;  // 4 x f32

#define CDIM 768

// ---------- bf16 helpers (raw ushort representation) ----------
__device__ __forceinline__ float bfu(ushort_t u) {
    return __uint_as_float(((uint)u) << 16);
}
__device__ __forceinline__ void bf2(uint u, float& lo, float& hi) {
    lo = __uint_as_float(u << 16);
    hi = __uint_as_float(u & 0xffff0000u);
}
__device__ __forceinline__ ushort_t f2bfu(float f) {
    uint u = __float_as_uint(f);
    u += 0x7fffu + ((u >> 16) & 1u);   // round-to-nearest-even
    return (ushort_t)(u >> 16);
}
__device__ __forceinline__ uint pack2(float a, float b) {     // RNE pack
    return (uint)f2bfu(a) | ((uint)f2bfu(b) << 16);
}
// packed RNE f32x2 -> bf16x2 (low word = first operand), 1 VALU inst
__device__ __forceinline__ uint cvt2(float lo, float hi) {
    uint r;
    asm("v_cvt_pk_bf16_f32 %0, %1, %2" : "=v"(r) : "v"(lo), "v"(hi));
    return r;
}
__device__ __forceinline__ short8 mk8(uint a, uint b, uint c, uint d) {
    union { uint4 u; short8 s; } x;
    x.u = (uint4){a, b, c, d};
    return x.s;
}
__device__ __forceinline__ void gload_lds16(const void* g, void* l) {
    __builtin_amdgcn_global_load_lds(
        (__attribute__((address_space(1))) void*)(uintptr_t)g,
        (__attribute__((address_space(3))) void*)l, 16, 0, 0);
}

// ---------- Kernel 0a: prep = cvt_w (864 blocks) + init_agent (96) + bias_ab (1) --
__global__ __launch_bounds__(256) void prep(
    const float* __restrict__ Wq, const float* __restrict__ Wk,
    const float* __restrict__ Wv, const float* __restrict__ bq,
    const float* __restrict__ na, const float* __restrict__ ha,
    const float* __restrict__ wa,
    ushort_t* __restrict__ wb, float* __restrict__ agent, float* __restrict__ ab)
{
    const int bid = blockIdx.x;
    if (bid < 864) {
        // cvt Wq/Wk/Wv (fp32) -> bf16 RNE
        const int m = bid / 288;
        const float* src = (m == 0) ? Wq : (m == 1 ? Wk : Wv);
        ushort_t* dst = wb + (size_t)m * 589824;
        const int i = ((bid % 288) * 256 + threadIdx.x) * 8;
        const float4 f0 = *(const float4*)(src + i);
        const float4 f1 = *(const float4*)(src + i + 4);
        uint4 u;
        u.x = pack2(f0.x, f0.y);
        u.y = pack2(f0.z, f0.w);
        u.z = pack2(f1.x, f1.y);
        u.w = pack2(f1.z, f1.w);
        *(uint4*)(dst + i) = u;
    } else if (bid < 960) {
        // init agent accumulator with the q-bias
        const int bh = bid - 864;
        const int h = bh % 12;
        for (int i = threadIdx.x; i < 1024; i += 256)
            agent[(size_t)bh * 1024 + i] = bq[h * 64 + (i & 63)];
    } else {
        // stage-2 agent bias ab[h][a]
        const int t = threadIdx.x;
        if (t >= 192) return;
        const int h = t >> 4, a = t & 15;
        const float cw[7] = {2.25f, 2.34375f, 2.28125f, 2.25f, 2.28125f, 2.34375f, 2.25f};
        float acc = 0.f;
        const float* nb = na + (h * 16 + a) * 49;
        for (int i = 0; i < 7; ++i)
            for (int j = 0; j < 7; ++j)
                acc += cw[i] * cw[j] * nb[i * 7 + j];
        acc *= (1.0f / 256.0f);
        float s = 0.f;
        for (int p = 0; p < 16; ++p)
            s += ha[(h * 16 + p) * 16 + a] + wa[(h * 16 + p) * 16 + a];
        ab[t] = acc + s * (1.0f / 16.0f);
    }
}

// ---------- Kernel 0b: convert s1/s2 (fp32) -> bf16 activations ----------
__global__ __launch_bounds__(256) void cvt_a(
    const float* __restrict__ s1, const float* __restrict__ s2,
    ushort_t* __restrict__ ab)
{
    const int m = blockIdx.y;
    const float* src = (m == 0) ? s1 : s2;
    ushort_t* dst = ab + (size_t)m * 25165824;
    const size_t i = ((size_t)blockIdx.x * 256 + threadIdx.x) * 8;  // 12288 blocks
    const float4 f0 = *(const float4*)(src + i);
    const float4 f1 = *(const float4*)(src + i + 4);
    uint4 u;
    u.x = pack2(f0.x, f0.y);
    u.y = pack2(f0.z, f0.w);
    u.z = pack2(f1.x, f1.y);
    u.w = pack2(f1.z, f1.w);
    *(uint4*)(dst + i) = u;
}

// ---------- Kernel 1: fused QKV GEMM (round-0 structure: all-bf16, pure
// global_load_lds staging) + XCD swizzle + fused agent pooling + LDS-staged
// coalesced epilogue (verified round 8: WRITE_SIZE at ideal 149 GB... KB) ----------
__global__ __launch_bounds__(256, 2) void gemm_qkv(
    const ushort_t* __restrict__ ab, const ushort_t* __restrict__ wb,
    const float* __restrict__ bq, const float* __restrict__ bk, const float* __restrict__ bv,
    ushort_t* __restrict__ qo, ushort_t* __restrict__ ko, ushort_t* __restrict__ vo,
    float* __restrict__ agent)
{
    const int z = blockIdx.z;
    const ushort_t* A     = ab + (size_t)(z != 0) * 25165824;
    const ushort_t* W     = wb + (size_t)z * 589824;
    const float* bias     = (z == 0) ? bq : (z == 1 ? bk : bv);
    ushort_t* out         = (z == 0) ? qo : (z == 1 ? ko : vo);

    __shared__ ushort_t lds[17408];     // 34,816 B: At=[0:8192], Wt=[8192:16384];
    ushort_t* At = lds;                 // epilogue reuses all as [128][136]
    ushort_t* Wt = lds + 8192;

    const int tid  = threadIdx.x;
    const int wave = tid >> 6;
    const int lane = tid & 63;
    const int wm = wave >> 1, wn = wave & 1;

    // XCD-aware swizzle: 1536 blocks/plane, 8 XCDs, 192 blocks/chunk (bijective).
    const int id   = blockIdx.x + (blockIdx.y << 8);   // gridDim.x = 256
    const int id2  = (id & 7) * 192 + (id >> 3);
    const int row0 = (id2 / 6) * 128;   // token rows (b*4096+m)
    const int col0 = (id2 % 6) * 128;   // output channels

    // staging: lane j covers row_off = j>>3, source chunk = (j&7) ^ (j>>3)
    const int sro = lane >> 3;
    const int sch = ((lane & 7) ^ sro) * 8;
    const ushort_t* gaBase = A + (size_t)(row0 + wave * 32 + sro) * CDIM + sch;
    const ushort_t* gwBase = W + (size_t)(col0 + wave * 32 + sro) * CDIM + sch;

    floatx4 acc[4][4];
    #pragma unroll
    for (int i = 0; i < 4; ++i)
        #pragma unroll
        for (int j = 0; j < 4; ++j)
            acc[i][j] = (floatx4){0.f, 0.f, 0.f, 0.f};

    const int q4 = lane >> 4, r16 = lane & 15;

    for (int kt = 0; kt < CDIM; kt += 64) {
        __syncthreads();
        #pragma unroll
        for (int i = 0; i < 4; ++i) {
            gload_lds16(gaBase + (size_t)i * 8 * CDIM + kt, &At[(wave * 32 + i * 8) * 64]);
            gload_lds16(gwBase + (size_t)i * 8 * CDIM + kt, &Wt[(wave * 32 + i * 8) * 64]);
        }
        __syncthreads();
        #pragma unroll
        for (int ks = 0; ks < 2; ++ks) {
            short8 af[4], bfr[4];
            #pragma unroll
            for (int mt = 0; mt < 4; ++mt) {
                const int row = wm * 64 + mt * 16 + r16;
                const int ch  = (ks * 4 + q4) ^ (row & 7);
                af[mt] = *(const short8*)&At[row * 64 + ch * 8];
            }
            #pragma unroll
            for (int nt = 0; nt < 4; ++nt) {
                const int row = wn * 64 + nt * 16 + r16;
                const int ch  = (ks * 4 + q4) ^ (row & 7);
                bfr[nt] = *(const short8*)&Wt[row * 64 + ch * 8];
            }
            #pragma unroll
            for (int mt = 0; mt < 4; ++mt)
                #pragma unroll
                for (int nt = 0; nt < 4; ++nt)
                    acc[mt][nt] = __builtin_amdgcn_mfma_f32_16x16x32_bf16(
                        af[mt], bfr[nt], acc[mt][nt], 0, 0, 0);
        }
    }

    // ---- epilogue: LDS-staged coalesced store + fused pool (z==0) ----
    __syncthreads();    // all LDS reads of the last K-tile complete
    const int b = row0 >> 12;
    const int m_base = row0 & 4095;
    #pragma unroll
    for (int nt = 0; nt < 4; ++nt) {
        const int coll = wn * 64 + nt * 16 + r16;     // col-local 0..127
        const float bb = bias[col0 + coll];
        float psum = 0.f;
        #pragma unroll
        for (int mt = 0; mt < 4; ++mt) {
            const int rowl = wm * 64 + mt * 16 + q4 * 4;
            #pragma unroll
            for (int r = 0; r < 4; ++r) {
                lds[(rowl + r) * 136 + coll] = f2bfu(acc[mt][nt][r] + bb);
                psum += acc[mt][nt][r];
            }
        }
        if (z == 0) {
            psum += __shfl_xor(psum, 16);
            psum += __shfl_xor(psum, 32);
            if (q4 == 0) {
                const int h = (col0 + coll) >> 6, d = (col0 + coll) & 63;
                atomicAdd(&agent[(size_t)(b * 12 + h) * 1024 + (m_base >> 8) * 64 + d],
                          psum * (1.0f / 256.0f));
            }
        }
    }
    __syncthreads();
    // 256 rows (128 m x 2 heads) x 128 B; 8 lanes per row, uint4 each.
    #pragma unroll
    for (int it = 0; it < 8; ++it) {
        const int task  = it * 256 + tid;
        const int chunk = task & 7;          // 16-B chunk within the row
        const int rh    = task >> 3;         // 0..255
        const int rowl  = rh >> 1, hl = rh & 1;
        const uint4 v = *(const uint4*)&lds[rowl * 136 + hl * 64 + chunk * 8];
        ushort_t* op = out + ((size_t)(b * 12 + (col0 >> 6) + hl) * 4096
                              + m_base + rowl) * 64 + chunk * 8;
        *(uint4*)op = v;
    }
}

// ---------- Kernel 4: stage 1 (agent -> keys/values), MFMA scores, z-split x16 --
// Part A (MFMA, stage2's verified swapped-operand pattern): S^T[a][tok] =
// mfma(A=ah(value+residual), B=K-rows); C/D col=lane&15=token, row=4g+r=agent.
// exp + pack2 -> one 8-B E2 store per lane (lands directly in [m][a] layout).
// Stage-1 softmax bias is constant along the softmax axis -> cancels (as before).
// Part B: two halves (half = tid>>8) each cover 128 m-rows; partials at
// z2 = 2z + half (32 partials total).
__global__ __launch_bounds__(512) void stage1(
    const ushort_t* __restrict__ k_hm, const ushort_t* __restrict__ v_hm,
    const float* __restrict__ agent, float* __restrict__ Sp, float* __restrict__ avp)
{
    const int bh = blockIdx.x, z = blockIdx.y;   // z in [0,16)
    const int tid = threadIdx.x;
    const int lane = tid & 63;
    const int w = tid >> 6;              // wave 0..7
    const int g = lane >> 4;             // quad group 0..3
    const int t = lane & 15;
    __shared__ ushort_t E2[256 * 20];    // [m_local][a] bf16, rows padded to 40 B

    // ah A-fragments (value + residual), scale 0.125 — identical to stage2's
    short8 ahA[2], ahE[2];
    #pragma unroll
    for (int k0 = 0; k0 < 2; ++k0) {
        const float* p = agent + (size_t)bh * 1024 + t * 64 + k0 * 32 + g * 8;
        const float4 f0 = *(const float4*)p;
        const float4 f1 = *(const float4*)(p + 4);
        const float v[8] = {f0.x, f0.y, f0.z, f0.w, f1.x, f1.y, f1.z, f1.w};
        uint u[4], e[4];
        #pragma unroll
        for (int j = 0; j < 4; ++j) {
            const float a0 = v[2*j] * 0.125f, a1 = v[2*j+1] * 0.125f;
            u[j] = cvt2(a0, a1);
            float b0, b1; bf2(u[j], b0, b1);
            e[j] = cvt2(a0 - b0, a1 - b1);
        }
        ahA[k0] = mk8(u[0], u[1], u[2], u[3]);
        ahE[k0] = mk8(e[0], e[1], e[2], e[3]);
    }

    const int m0 = z * 256;
    const ushort_t* kb = k_hm + ((size_t)bh * 4096 + m0) * 64;

    #pragma unroll
    for (int ti = 0; ti < 2; ++ti) {
        const int row = w * 32 + ti * 16 + t;
        const ushort_t* kp = kb + (size_t)row * 64 + g * 8;
        const short8 kB0 = *(const short8*)(kp);
        const short8 kB1 = *(const short8*)(kp + 32);
        floatx4 sc = {0.f, 0.f, 0.f, 0.f};
        sc = __builtin_amdgcn_mfma_f32_16x16x32_bf16(ahA[0], kB0, sc, 0, 0, 0);
        sc = __builtin_amdgcn_mfma_f32_16x16x32_bf16(ahA[1], kB1, sc, 0, 0, 0);
        sc = __builtin_amdgcn_mfma_f32_16x16x32_bf16(ahE[0], kB0, sc, 0, 0, 0);
        sc = __builtin_amdgcn_mfma_f32_16x16x32_bf16(ahE[1], kB1, sc, 0, 0, 0);
        const uint P0 = pack2(__expf(sc[0]), __expf(sc[1]));
        const uint P1 = pack2(__expf(sc[2]), __expf(sc[3]));
        *(uint2*)&E2[(size_t)row * 20 + g * 4] = make_uint2(P0, P1);
    }
    __syncthreads();

    const int d = tid & 63, gg = (tid >> 6) & 3, half = tid >> 8;
    const int mb = half * 128;
    const ushort_t* vb = v_hm + ((size_t)bh * 4096 + m0 + mb) * 64 + d;
    float acc0 = 0, acc1 = 0, acc2 = 0, acc3 = 0;
    float ss0 = 0, ss1 = 0, ss2 = 0, ss3 = 0;
    for (int ml = 0; ml < 128; ++ml) {
        const float vv = bfu(vb[(size_t)ml * 64]);
        const uint2 ee = *(const uint2*)&E2[(size_t)(mb + ml) * 20 + gg * 4];
        float e0, e1, e2, e3;
        bf2(ee.x, e0, e1);
        bf2(ee.y, e2, e3);
        acc0 += e0 * vv; ss0 += e0;
        acc1 += e1 * vv; ss1 += e1;
        acc2 += e2 * vv; ss2 += e2;
        acc3 += e3 * vv; ss3 += e3;
    }
    const int z2 = z * 2 + half;         // 0..31
    float* avz = avp + (size_t)(z2 * 96 + bh) * 1024;
    avz[(gg * 4 + 0) * 64 + d] = acc0;
    avz[(gg * 4 + 1) * 64 + d] = acc1;
    avz[(gg * 4 + 2) * 64 + d] = acc2;
    avz[(gg * 4 + 3) * 64 + d] = acc3;
    if (d == 0) {
        float* Sz = Sp + (z2 * 96 + bh) * 16;
        Sz[gg * 4 + 0] = ss0;
        Sz[gg * 4 + 1] = ss1;
        Sz[gg * 4 + 2] = ss2;
        Sz[gg * 4 + 3] = ss3;
    }
}

// ---------- Kernel 5: stage 2 (queries -> agents) via MFMA ----------
// Swapped-operand scheme (verified round 5). 32 partials.
__global__ __launch_bounds__(256) void stage2(
    const ushort_t* __restrict__ q_hm, const float* __restrict__ avp,
    const float* __restrict__ Sp, const float* __restrict__ agent,
    const float* __restrict__ ab, float* __restrict__ out)
{
    const int nb = blockIdx.x;           // 16
    const int bh = blockIdx.y;           // 96
    const int b = bh / 12, h = bh % 12;
    const int tid = threadIdx.x;
    const int g = (tid >> 4) & 3;        // lane>>4 (quad group)
    const int t = tid & 15;              // lane&15
    const int w = tid >> 6;              // wave
    __shared__ float avn[1024];          // normalized agent_v, [a][d] fp32

    // avn = (sum_z2 avp) / (sum_z2 Sp)
    {
        const int i4 = tid * 4;
        const int a = i4 >> 6;
        floatx4 num = {0.f, 0.f, 0.f, 0.f};
        float den = 0.f;
        #pragma unroll
        for (int zz = 0; zz < 32; ++zz) {
            num += *(const floatx4*)&avp[(size_t)(zz * 96 + bh) * 1024 + i4];
            den += Sp[(zz * 96 + bh) * 16 + a];
        }
        const float r = 1.0f / den;
        *(floatx4*)&avn[i4] = num * r;
    }
    __syncthreads();

    // ah A-fragments (value + residual): lane holds ah[t][k0*32 + g*8 + j]*scale
    short8 ahA[2], ahE[2];
    #pragma unroll
    for (int k0 = 0; k0 < 2; ++k0) {
        const float* p = agent + (size_t)bh * 1024 + t * 64 + k0 * 32 + g * 8;
        const float4 f0 = *(const float4*)p;
        const float4 f1 = *(const float4*)(p + 4);
        const float v[8] = {f0.x, f0.y, f0.z, f0.w, f1.x, f1.y, f1.z, f1.w};
        uint u[4], e[4];
        #pragma unroll
        for (int j = 0; j < 4; ++j) {
            const float a0 = v[2*j] * 0.125f, a1 = v[2*j+1] * 0.125f;
            u[j] = cvt2(a0, a1);
            float b0, b1; bf2(u[j], b0, b1);
            e[j] = cvt2(a0 - b0, a1 - b1);
        }
        ahA[k0] = mk8(u[0], u[1], u[2], u[3]);
        ahE[k0] = mk8(e[0], e[1], e[2], e[3]);
    }

    // av^T A-fragments (value + residual): lane holds avn[8g+j][dt*16 + t]; g>=2 zero
    short8 avf[4], ave[4];
    #pragma unroll
    for (int dt = 0; dt < 4; ++dt) {
        uint u[4] = {0, 0, 0, 0}, e[4] = {0, 0, 0, 0};
        if (g < 2) {
            #pragma unroll
            for (int j = 0; j < 4; ++j) {
                const float a0 = avn[(8*g + 2*j)     * 64 + dt * 16 + t];
                const float a1 = avn[(8*g + 2*j + 1) * 64 + dt * 16 + t];
                u[j] = cvt2(a0, a1);
                float b0, b1; bf2(u[j], b0, b1);
                e[j] = cvt2(a0 - b0, a1 - b1);
            }
        }
        avf[dt] = mk8(u[0], u[1], u[2], u[3]);
        ave[dt] = mk8(e[0], e[1], e[2], e[3]);
    }

    float abv[4];
    #pragma unroll
    for (int r = 0; r < 4; ++r) abv[r] = ab[h * 16 + 4 * g + r];

    const int src0 = (t + 32 * g) & 63;
    const int src1 = (src0 + 16) & 63;
    const int n0 = nb * 256 + w * 64;
    const ushort_t* qb = q_hm + ((size_t)bh * 4096 + n0) * 64;
    float* ob = out + ((size_t)b * 4096 + n0) * CDIM + h * 64;

    #pragma unroll
    for (int ti = 0; ti < 4; ++ti) {
        // Q B-fragments: lane holds Q[ti*16+t][k0*32 + g*8 + j]
        const ushort_t* qp = qb + (size_t)(ti * 16 + t) * 64 + g * 8;
        const short8 qB0 = *(const short8*)(qp);
        const short8 qB1 = *(const short8*)(qp + 32);

        floatx4 sc = {0.f, 0.f, 0.f, 0.f};
        sc = __builtin_amdgcn_mfma_f32_16x16x32_bf16(ahA[0], qB0, sc, 0, 0, 0);
        sc = __builtin_amdgcn_mfma_f32_16x16x32_bf16(ahA[1], qB1, sc, 0, 0, 0);
        sc = __builtin_amdgcn_mfma_f32_16x16x32_bf16(ahE[0], qB0, sc, 0, 0, 0);
        sc = __builtin_amdgcn_mfma_f32_16x16x32_bf16(ahE[1], qB1, sc, 0, 0, 0);

        // softmax over agents (rows): in-lane + cross-group
        const float e0 = __expf(sc[0] + abv[0]);
        const float e1 = __expf(sc[1] + abv[1]);
        const float e2 = __expf(sc[2] + abv[2]);
        const float e3 = __expf(sc[3] + abv[3]);
        float s = e0 + e1 + e2 + e3;
        s += __shfl_xor(s, 16);
        s += __shfl_xor(s, 32);
        const float rs = 1.0f / s;
        const float p0 = e0 * rs, p1 = e1 * rs, p2 = e2 * rs, p3 = e3 * rs;

        // pack own P (agents 4g..4g+3, token t) + residual
        const uint P0 = cvt2(p0, p1), P1 = cvt2(p2, p3);
        float q0, q1, q2, q3;
        bf2(P0, q0, q1); bf2(P1, q2, q3);
        const uint E0 = cvt2(p0 - q0, p1 - q1), E1 = cvt2(p2 - q2, p3 - q3);

        // regroup into K=32-padded B-fragment: k=8g+j -> agents from groups 2g, 2g+1
        uint w0 = __shfl(P0, src0), w1 = __shfl(P1, src0);
        uint w2 = __shfl(P0, src1), w3 = __shfl(P1, src1);
        uint x0 = __shfl(E0, src0), x1 = __shfl(E1, src0);
        uint x2 = __shfl(E0, src1), x3 = __shfl(E1, src1);
        if (g >= 2) { w0 = w1 = w2 = w3 = 0; x0 = x1 = x2 = x3 = 0; }
        const short8 pf = mk8(w0, w1, w2, w3);
        const short8 pe = mk8(x0, x1, x2, x3);

        // PV: out^T[dt*16 + 4g + r][t], residual-corrected
        float* op = ob + (size_t)(ti * 16 + t) * CDIM + 4 * g;
        #pragma unroll
        for (int dt = 0; dt < 4; ++dt) {
            floatx4 od = {0.f, 0.f, 0.f, 0.f};
            od = __builtin_amdgcn_mfma_f32_16x16x32_bf16(avf[dt], pf, od, 0, 0, 0);
            od = __builtin_amdgcn_mfma_f32_16x16x32_bf16(avf[dt], pe, od, 0, 0, 0);
            od = __builtin_amdgcn_mfma_f32_16x16x32_bf16(ave[dt], pf, od, 0, 0, 0);
            *(floatx4*)(op + dt * 16) = od;
        }
    }
}

// ---------- launcher ----------
extern "C" void kernel_launch(void* const* d_in, const int* in_sizes, int n_in,
                              void* d_out, int out_size, void* d_ws, size_t ws_size,
                              hipStream_t stream) {
    (void)in_sizes; (void)n_in; (void)out_size; (void)ws_size;
    const float* s1 = (const float*)d_in[0];
    const float* s2 = (const float*)d_in[1];
    const float* Wq = (const float*)d_in[2];
    const float* bq = (const float*)d_in[3];
    const float* Wk = (const float*)d_in[4];
    const float* bk = (const float*)d_in[5];
    const float* Wv = (const float*)d_in[6];
    const float* bv = (const float*)d_in[7];
    const float* na = (const float*)d_in[9];
    const float* ha = (const float*)d_in[12];
    const float* wa = (const float*)d_in[13];
    float* out = (float*)d_out;

    char* ws = (char*)d_ws;
    ushort_t* q_hm = (ushort_t*)(ws);                 // 50,331,648 B  [96][4096][64]
    ushort_t* k_hm = (ushort_t*)(ws + 50331648);      // 50,331,648 B
    ushort_t* v_hm = (ushort_t*)(ws + 100663296);     // 50,331,648 B
    float* agent   = (float*)(ws + 150994944);        //    393,216 B  [96][16][64]
    float* Sp      = (float*)(ws + 151388160);        //    196,608 B  [32][96][16]
    float* ab      = (float*)(ws + 151584768);        //        768 B
    ushort_t* wb   = (ushort_t*)(ws + 151585536);     //  3,538,944 B  [3][768][768]
    ushort_t* abuf = (ushort_t*)(ws + 155124480);     // 100,663,296 B [2][32768][768]  (live cvt_a..gemm)
    float* avp     = (float*)(ws + 155124480);        // 12,582,912 B  [32][96][16][64] (live stage1..stage2, overlays dead abuf)

    prep     <<<dim3(961),       256, 0, stream>>>(Wq, Wk, Wv, bq, na, ha, wa,
                                                   wb, agent, ab);
    cvt_a    <<<dim3(12288, 2),  256, 0, stream>>>(s1, s2, abuf);
    gemm_qkv <<<dim3(256, 6, 3), 256, 0, stream>>>(abuf, wb, bq, bk, bv,
                                                   q_hm, k_hm, v_hm, agent);
    stage1   <<<dim3(96, 16),    512, 0, stream>>>(k_hm, v_hm, agent, Sp, avp);
    stage2   <<<dim3(16, 96),    256, 0, stream>>>(q_hm, avp, Sp, agent, ab, out);
}

// Round 10
// 268.493 us; speedup vs baseline: 1.1638x; 1.0364x over previous
//
#include <hip/hip_runtime.h>
#include <cstdint>
#include <cstddef>

typedef unsigned short ushort_t;
typedef unsigned int uint;

typedef __attribute__((ext_vector_type(8))) short short8;   // 8 x bf16 (4 VGPRs)
typedef __attribute__((ext_vector_type(4))) float floatx4;  // 4 x f32

#define CDIM 768

// ---------- bf16 helpers (raw ushort representation) ----------
__device__ __forceinline__ float bfu(ushort_t u) {
    return __uint_as_float(((uint)u) << 16);
}
__device__ __forceinline__ void bf2(uint u, float& lo, float& hi) {
    lo = __uint_as_float(u << 16);
    hi = __uint_as_float(u & 0xffff0000u);
}
__device__ __forceinline__ ushort_t f2bfu(float f) {
    uint u = __float_as_uint(f);
    u += 0x7fffu + ((u >> 16) & 1u);   // round-to-nearest-even
    return (ushort_t)(u >> 16);
}
__device__ __forceinline__ uint pack2(float a, float b) {     // RNE pack
    return (uint)f2bfu(a) | ((uint)f2bfu(b) << 16);
}
// packed RNE f32x2 -> bf16x2 (low word = first operand), 1 VALU inst
__device__ __forceinline__ uint cvt2(float lo, float hi) {
    uint r;
    asm("v_cvt_pk_bf16_f32 %0, %1, %2" : "=v"(r) : "v"(lo), "v"(hi));
    return r;
}
__device__ __forceinline__ short8 mk8(uint a, uint b, uint c, uint d) {
    union { uint4 u; short8 s; } x;
    x.u = (uint4){a, b, c, d};
    return x.s;
}
__device__ __forceinline__ void gload_lds16(const void* g, void* l) {
    __builtin_amdgcn_global_load_lds(
        (__attribute__((address_space(1))) void*)(uintptr_t)g,
        (__attribute__((address_space(3))) void*)l, 16, 0, 0);
}

// ---------- Kernel 0a: prep = cvt_w (864 blocks) + init_agent (96) + bias_ab (1) --
__global__ __launch_bounds__(256) void prep(
    const float* __restrict__ Wq, const float* __restrict__ Wk,
    const float* __restrict__ Wv, const float* __restrict__ bq,
    const float* __restrict__ na, const float* __restrict__ ha,
    const float* __restrict__ wa,
    ushort_t* __restrict__ wb, float* __restrict__ agent, float* __restrict__ ab)
{
    const int bid = blockIdx.x;
    if (bid < 864) {
        // cvt Wq/Wk/Wv (fp32) -> bf16 RNE
        const int m = bid / 288;
        const float* src = (m == 0) ? Wq : (m == 1 ? Wk : Wv);
        ushort_t* dst = wb + (size_t)m * 589824;
        const int i = ((bid % 288) * 256 + threadIdx.x) * 8;
        const float4 f0 = *(const float4*)(src + i);
        const float4 f1 = *(const float4*)(src + i + 4);
        uint4 u;
        u.x = pack2(f0.x, f0.y);
        u.y = pack2(f0.z, f0.w);
        u.z = pack2(f1.x, f1.y);
        u.w = pack2(f1.z, f1.w);
        *(uint4*)(dst + i) = u;
    } else if (bid < 960) {
        // init agent accumulator with the q-bias
        const int bh = bid - 864;
        const int h = bh % 12;
        for (int i = threadIdx.x; i < 1024; i += 256)
            agent[(size_t)bh * 1024 + i] = bq[h * 64 + (i & 63)];
    } else {
        // stage-2 agent bias ab[h][a]
        const int t = threadIdx.x;
        if (t >= 192) return;
        const int h = t >> 4, a = t & 15;
        const float cw[7] = {2.25f, 2.34375f, 2.28125f, 2.25f, 2.28125f, 2.34375f, 2.25f};
        float acc = 0.f;
        const float* nb = na + (h * 16 + a) * 49;
        for (int i = 0; i < 7; ++i)
            for (int j = 0; j < 7; ++j)
                acc += cw[i] * cw[j] * nb[i * 7 + j];
        acc *= (1.0f / 256.0f);
        float s = 0.f;
        for (int p = 0; p < 16; ++p)
            s += ha[(h * 16 + p) * 16 + a] + wa[(h * 16 + p) * 16 + a];
        ab[t] = acc + s * (1.0f / 16.0f);
    }
}

// ---------- Kernel 0b: convert s1/s2 (fp32) -> bf16 activations ----------
__global__ __launch_bounds__(256) void cvt_a(
    const float* __restrict__ s1, const float* __restrict__ s2,
    ushort_t* __restrict__ ab)
{
    const int m = blockIdx.y;
    const float* src = (m == 0) ? s1 : s2;
    ushort_t* dst = ab + (size_t)m * 25165824;
    const size_t i = ((size_t)blockIdx.x * 256 + threadIdx.x) * 8;  // 12288 blocks
    const float4 f0 = *(const float4*)(src + i);
    const float4 f1 = *(const float4*)(src + i + 4);
    uint4 u;
    u.x = pack2(f0.x, f0.y);
    u.y = pack2(f0.z, f0.w);
    u.z = pack2(f1.x, f1.y);
    u.w = pack2(f1.z, f1.w);
    *(uint4*)(dst + i) = u;
}

// ---------- Kernel 1: fused QKV GEMM (round-0 structure: all-bf16, pure
// global_load_lds staging) + XCD swizzle + fused agent pooling + LDS-staged
// coalesced epilogue (verified round 8: WRITE_SIZE at ideal 148,992 KB) ----------
__global__ __launch_bounds__(256, 2) void gemm_qkv(
    const ushort_t* __restrict__ ab, const ushort_t* __restrict__ wb,
    const float* __restrict__ bq, const float* __restrict__ bk, const float* __restrict__ bv,
    ushort_t* __restrict__ qo, ushort_t* __restrict__ ko, ushort_t* __restrict__ vo,
    float* __restrict__ agent)
{
    const int z = blockIdx.z;
    const ushort_t* A     = ab + (size_t)(z != 0) * 25165824;
    const ushort_t* W     = wb + (size_t)z * 589824;
    const float* bias     = (z == 0) ? bq : (z == 1 ? bk : bv);
    ushort_t* out         = (z == 0) ? qo : (z == 1 ? ko : vo);

    __shared__ ushort_t lds[17408];     // 34,816 B: At=[0:8192], Wt=[8192:16384];
    ushort_t* At = lds;                 // epilogue reuses all as [128][136]
    ushort_t* Wt = lds + 8192;

    const int tid  = threadIdx.x;
    const int wave = tid >> 6;
    const int lane = tid & 63;
    const int wm = wave >> 1, wn = wave & 1;

    // XCD-aware swizzle: 1536 blocks/plane, 8 XCDs, 192 blocks/chunk (bijective).
    const int id   = blockIdx.x + (blockIdx.y << 8);   // gridDim.x = 256
    const int id2  = (id & 7) * 192 + (id >> 3);
    const int row0 = (id2 / 6) * 128;   // token rows (b*4096+m)
    const int col0 = (id2 % 6) * 128;   // output channels

    // staging: lane j covers row_off = j>>3, source chunk = (j&7) ^ (j>>3)
    const int sro = lane >> 3;
    const int sch = ((lane & 7) ^ sro) * 8;
    const ushort_t* gaBase = A + (size_t)(row0 + wave * 32 + sro) * CDIM + sch;
    const ushort_t* gwBase = W + (size_t)(col0 + wave * 32 + sro) * CDIM + sch;

    floatx4 acc[4][4];
    #pragma unroll
    for (int i = 0; i < 4; ++i)
        #pragma unroll
        for (int j = 0; j < 4; ++j)
            acc[i][j] = (floatx4){0.f, 0.f, 0.f, 0.f};

    const int q4 = lane >> 4, r16 = lane & 15;

    for (int kt = 0; kt < CDIM; kt += 64) {
        __syncthreads();
        #pragma unroll
        for (int i = 0; i < 4; ++i) {
            gload_lds16(gaBase + (size_t)i * 8 * CDIM + kt, &At[(wave * 32 + i * 8) * 64]);
            gload_lds16(gwBase + (size_t)i * 8 * CDIM + kt, &Wt[(wave * 32 + i * 8) * 64]);
        }
        __syncthreads();
        #pragma unroll
        for (int ks = 0; ks < 2; ++ks) {
            short8 af[4], bfr[4];
            #pragma unroll
            for (int mt = 0; mt < 4; ++mt) {
                const int row = wm * 64 + mt * 16 + r16;
                const int ch  = (ks * 4 + q4) ^ (row & 7);
                af[mt] = *(const short8*)&At[row * 64 + ch * 8];
            }
            #pragma unroll
            for (int nt = 0; nt < 4; ++nt) {
                const int row = wn * 64 + nt * 16 + r16;
                const int ch  = (ks * 4 + q4) ^ (row & 7);
                bfr[nt] = *(const short8*)&Wt[row * 64 + ch * 8];
            }
            #pragma unroll
            for (int mt = 0; mt < 4; ++mt)
                #pragma unroll
                for (int nt = 0; nt < 4; ++nt)
                    acc[mt][nt] = __builtin_amdgcn_mfma_f32_16x16x32_bf16(
                        af[mt], bfr[nt], acc[mt][nt], 0, 0, 0);
        }
    }

    // ---- epilogue: LDS-staged coalesced store + fused pool (z==0) ----
    __syncthreads();    // all LDS reads of the last K-tile complete
    const int b = row0 >> 12;
    const int m_base = row0 & 4095;
    #pragma unroll
    for (int nt = 0; nt < 4; ++nt) {
        const int coll = wn * 64 + nt * 16 + r16;     // col-local 0..127
        const float bb = bias[col0 + coll];
        float psum = 0.f;
        #pragma unroll
        for (int mt = 0; mt < 4; ++mt) {
            const int rowl = wm * 64 + mt * 16 + q4 * 4;
            #pragma unroll
            for (int r = 0; r < 4; ++r) {
                lds[(rowl + r) * 136 + coll] = f2bfu(acc[mt][nt][r] + bb);
                psum += acc[mt][nt][r];
            }
        }
        if (z == 0) {
            psum += __shfl_xor(psum, 16);
            psum += __shfl_xor(psum, 32);
            if (q4 == 0) {
                const int h = (col0 + coll) >> 6, d = (col0 + coll) & 63;
                atomicAdd(&agent[(size_t)(b * 12 + h) * 1024 + (m_base >> 8) * 64 + d],
                          psum * (1.0f / 256.0f));
            }
        }
    }
    __syncthreads();
    // 256 rows (128 m x 2 heads) x 128 B; 8 lanes per row, uint4 each.
    #pragma unroll
    for (int it = 0; it < 8; ++it) {
        const int task  = it * 256 + tid;
        const int chunk = task & 7;          // 16-B chunk within the row
        const int rh    = task >> 3;         // 0..255
        const int rowl  = rh >> 1, hl = rh & 1;
        const uint4 v = *(const uint4*)&lds[rowl * 136 + hl * 64 + chunk * 8];
        ushort_t* op = out + ((size_t)(b * 12 + (col0 >> 6) + hl) * 4096
                              + m_base + rowl) * 64 + chunk * 8;
        *(uint4*)op = v;
    }
}

// ---------- Kernel 4: stage 1 (agent -> keys/values), MFMA scores, z-split x16 --
// Part A (MFMA, verified round 9): S^T[a][tok] = mfma(A=ah(value+residual),
// B=K-rows); exp + pack2 -> 8-B E2 store per lane.
// Part B (vectorized this round): lane covers a d-PAIR (uint loads, 4 B),
// lanes split 2-way over m (mseg); partials combined via shfl_xor(32);
// float2 stores. Sp stored transposed [bh][a][z2] for stage2's contiguous read.
__global__ __launch_bounds__(512) void stage1(
    const ushort_t* __restrict__ k_hm, const ushort_t* __restrict__ v_hm,
    const float* __restrict__ agent, float* __restrict__ Sp, float* __restrict__ avp)
{
    const int bh = blockIdx.x, z = blockIdx.y;   // z in [0,16)
    const int tid = threadIdx.x;
    const int lane = tid & 63;
    const int w = tid >> 6;              // wave 0..7
    const int g = lane >> 4;             // quad group 0..3
    const int t = lane & 15;
    __shared__ ushort_t E2[256 * 20];    // [m_local][a] bf16, rows padded to 40 B

    // ah A-fragments (value + residual), scale 0.125 — identical to stage2's
    short8 ahA[2], ahE[2];
    #pragma unroll
    for (int k0 = 0; k0 < 2; ++k0) {
        const float* p = agent + (size_t)bh * 1024 + t * 64 + k0 * 32 + g * 8;
        const float4 f0 = *(const float4*)p;
        const float4 f1 = *(const float4*)(p + 4);
        const float v[8] = {f0.x, f0.y, f0.z, f0.w, f1.x, f1.y, f1.z, f1.w};
        uint u[4], e[4];
        #pragma unroll
        for (int j = 0; j < 4; ++j) {
            const float a0 = v[2*j] * 0.125f, a1 = v[2*j+1] * 0.125f;
            u[j] = cvt2(a0, a1);
            float b0, b1; bf2(u[j], b0, b1);
            e[j] = cvt2(a0 - b0, a1 - b1);
        }
        ahA[k0] = mk8(u[0], u[1], u[2], u[3]);
        ahE[k0] = mk8(e[0], e[1], e[2], e[3]);
    }

    const int m0 = z * 256;
    const ushort_t* kb = k_hm + ((size_t)bh * 4096 + m0) * 64;

    #pragma unroll
    for (int ti = 0; ti < 2; ++ti) {
        const int row = w * 32 + ti * 16 + t;
        const ushort_t* kp = kb + (size_t)row * 64 + g * 8;
        const short8 kB0 = *(const short8*)(kp);
        const short8 kB1 = *(const short8*)(kp + 32);
        floatx4 sc = {0.f, 0.f, 0.f, 0.f};
        sc = __builtin_amdgcn_mfma_f32_16x16x32_bf16(ahA[0], kB0, sc, 0, 0, 0);
        sc = __builtin_amdgcn_mfma_f32_16x16x32_bf16(ahA[1], kB1, sc, 0, 0, 0);
        sc = __builtin_amdgcn_mfma_f32_16x16x32_bf16(ahE[0], kB0, sc, 0, 0, 0);
        sc = __builtin_amdgcn_mfma_f32_16x16x32_bf16(ahE[1], kB1, sc, 0, 0, 0);
        const uint P0 = pack2(__expf(sc[0]), __expf(sc[1]));
        const uint P1 = pack2(__expf(sc[2]), __expf(sc[3]));
        *(uint2*)&E2[(size_t)row * 20 + g * 4] = make_uint2(P0, P1);
    }
    __syncthreads();

    // part B: quad gg of agents, half of m (128 rows), mseg splits it 2x64;
    // lane ls covers d-pair (d0, d0+1).
    const int gg = (tid >> 6) & 3;
    const int half = tid >> 8;           // 0/1
    const int ls = lane & 31;
    const int mseg = lane >> 5;          // 0/1
    const int d0 = ls * 2;
    const int mb = half * 128 + mseg * 64;
    const ushort_t* vb = v_hm + ((size_t)bh * 4096 + m0 + mb) * 64 + d0;
    float ac[4][2];
    float ss[4];
    #pragma unroll
    for (int a = 0; a < 4; ++a) { ac[a][0] = 0.f; ac[a][1] = 0.f; ss[a] = 0.f; }
    for (int ml = 0; ml < 64; ++ml) {
        const uint vv = *(const uint*)(vb + (size_t)ml * 64);
        float v0, v1;
        bf2(vv, v0, v1);
        const uint2 ee = *(const uint2*)&E2[(size_t)(mb + ml) * 20 + gg * 4];
        float e0, e1, e2, e3;
        bf2(ee.x, e0, e1);
        bf2(ee.y, e2, e3);
        ac[0][0] += e0 * v0; ac[0][1] += e0 * v1; ss[0] += e0;
        ac[1][0] += e1 * v0; ac[1][1] += e1 * v1; ss[1] += e1;
        ac[2][0] += e2 * v0; ac[2][1] += e2 * v1; ss[2] += e2;
        ac[3][0] += e3 * v0; ac[3][1] += e3 * v1; ss[3] += e3;
    }
    #pragma unroll
    for (int a = 0; a < 4; ++a) {
        ac[a][0] += __shfl_xor(ac[a][0], 32);
        ac[a][1] += __shfl_xor(ac[a][1], 32);
        ss[a]    += __shfl_xor(ss[a], 32);
    }
    const int z2 = z * 2 + half;         // 0..31
    if (mseg == 0) {
        float* avz = avp + (size_t)(z2 * 96 + bh) * 1024;
        #pragma unroll
        for (int a = 0; a < 4; ++a)
            *(float2*)&avz[(gg * 4 + a) * 64 + d0] = make_float2(ac[a][0], ac[a][1]);
        if (ls == 0) {
            #pragma unroll
            for (int a = 0; a < 4; ++a)
                Sp[((size_t)bh * 16 + gg * 4 + a) * 32 + z2] = ss[a];
        }
    }
}

// ---------- Kernel 5: stage 2 (queries -> agents) via MFMA ----------
// Swapped-operand scheme (verified round 5). 32 partials; Sp transposed.
__global__ __launch_bounds__(256) void stage2(
    const ushort_t* __restrict__ q_hm, const float* __restrict__ avp,
    const float* __restrict__ Sp, const float* __restrict__ agent,
    const float* __restrict__ ab, float* __restrict__ out)
{
    const int nb = blockIdx.x;           // 16
    const int bh = blockIdx.y;           // 96
    const int b = bh / 12, h = bh % 12;
    const int tid = threadIdx.x;
    const int g = (tid >> 4) & 3;        // lane>>4 (quad group)
    const int t = tid & 15;              // lane&15
    const int w = tid >> 6;              // wave
    __shared__ float avn[1024];          // normalized agent_v, [a][d] fp32

    // avn = (sum_z2 avp) / (sum_z2 Sp); Sp is [bh][a][z2] -> contiguous loads
    {
        const int i4 = tid * 4;
        const int a = i4 >> 6;
        floatx4 num = {0.f, 0.f, 0.f, 0.f};
        #pragma unroll
        for (int zz = 0; zz < 32; ++zz)
            num += *(const floatx4*)&avp[(size_t)(zz * 96 + bh) * 1024 + i4];
        const float* sp = Sp + ((size_t)bh * 16 + a) * 32;
        floatx4 dv = {0.f, 0.f, 0.f, 0.f};
        #pragma unroll
        for (int j = 0; j < 8; ++j)
            dv += *(const floatx4*)(sp + j * 4);
        const float r = 1.0f / (dv[0] + dv[1] + dv[2] + dv[3]);
        *(floatx4*)&avn[i4] = num * r;
    }
    __syncthreads();

    // ah A-fragments (value + residual): lane holds ah[t][k0*32 + g*8 + j]*scale
    short8 ahA[2], ahE[2];
    #pragma unroll
    for (int k0 = 0; k0 < 2; ++k0) {
        const float* p = agent + (size_t)bh * 1024 + t * 64 + k0 * 32 + g * 8;
        const float4 f0 = *(const float4*)p;
        const float4 f1 = *(const float4*)(p + 4);
        const float v[8] = {f0.x, f0.y, f0.z, f0.w, f1.x, f1.y, f1.z, f1.w};
        uint u[4], e[4];
        #pragma unroll
        for (int j = 0; j < 4; ++j) {
            const float a0 = v[2*j] * 0.125f, a1 = v[2*j+1] * 0.125f;
            u[j] = cvt2(a0, a1);
            float b0, b1; bf2(u[j], b0, b1);
            e[j] = cvt2(a0 - b0, a1 - b1);
        }
        ahA[k0] = mk8(u[0], u[1], u[2], u[3]);
        ahE[k0] = mk8(e[0], e[1], e[2], e[3]);
    }

    // av^T A-fragments (value + residual): lane holds avn[8g+j][dt*16 + t]; g>=2 zero
    short8 avf[4], ave[4];
    #pragma unroll
    for (int dt = 0; dt < 4; ++dt) {
        uint u[4] = {0, 0, 0, 0}, e[4] = {0, 0, 0, 0};
        if (g < 2) {
            #pragma unroll
            for (int j = 0; j < 4; ++j) {
                const float a0 = avn[(8*g + 2*j)     * 64 + dt * 16 + t];
                const float a1 = avn[(8*g + 2*j + 1) * 64 + dt * 16 + t];
                u[j] = cvt2(a0, a1);
                float b0, b1; bf2(u[j], b0, b1);
                e[j] = cvt2(a0 - b0, a1 - b1);
            }
        }
        avf[dt] = mk8(u[0], u[1], u[2], u[3]);
        ave[dt] = mk8(e[0], e[1], e[2], e[3]);
    }

    float abv[4];
    #pragma unroll
    for (int r = 0; r < 4; ++r) abv[r] = ab[h * 16 + 4 * g + r];

    const int src0 = (t + 32 * g) & 63;
    const int src1 = (src0 + 16) & 63;
    const int n0 = nb * 256 + w * 64;
    const ushort_t* qb = q_hm + ((size_t)bh * 4096 + n0) * 64;
    float* ob = out + ((size_t)b * 4096 + n0) * CDIM + h * 64;

    #pragma unroll
    for (int ti = 0; ti < 4; ++ti) {
        // Q B-fragments: lane holds Q[ti*16+t][k0*32 + g*8 + j]
        const ushort_t* qp = qb + (size_t)(ti * 16 + t) * 64 + g * 8;
        const short8 qB0 = *(const short8*)(qp);
        const short8 qB1 = *(const short8*)(qp + 32);

        floatx4 sc = {0.f, 0.f, 0.f, 0.f};
        sc = __builtin_amdgcn_mfma_f32_16x16x32_bf16(ahA[0], qB0, sc, 0, 0, 0);
        sc = __builtin_amdgcn_mfma_f32_16x16x32_bf16(ahA[1], qB1, sc, 0, 0, 0);
        sc = __builtin_amdgcn_mfma_f32_16x16x32_bf16(ahE[0], qB0, sc, 0, 0, 0);
        sc = __builtin_amdgcn_mfma_f32_16x16x32_bf16(ahE[1], qB1, sc, 0, 0, 0);

        // softmax over agents (rows): in-lane + cross-group
        const float e0 = __expf(sc[0] + abv[0]);
        const float e1 = __expf(sc[1] + abv[1]);
        const float e2 = __expf(sc[2] + abv[2]);
        const float e3 = __expf(sc[3] + abv[3]);
        float s = e0 + e1 + e2 + e3;
        s += __shfl_xor(s, 16);
        s += __shfl_xor(s, 32);
        const float rs = 1.0f / s;
        const float p0 = e0 * rs, p1 = e1 * rs, p2 = e2 * rs, p3 = e3 * rs;

        // pack own P (agents 4g..4g+3, token t) + residual
        const uint P0 = cvt2(p0, p1), P1 = cvt2(p2, p3);
        float q0, q1, q2, q3;
        bf2(P0, q0, q1); bf2(P1, q2, q3);
        const uint E0 = cvt2(p0 - q0, p1 - q1), E1 = cvt2(p2 - q2, p3 - q3);

        // regroup into K=32-padded B-fragment: k=8g+j -> agents from groups 2g, 2g+1
        uint w0 = __shfl(P0, src0), w1 = __shfl(P1, src0);
        uint w2 = __shfl(P0, src1), w3 = __shfl(P1, src1);
        uint x0 = __shfl(E0, src0), x1 = __shfl(E1, src0);
        uint x2 = __shfl(E0, src1), x3 = __shfl(E1, src1);
        if (g >= 2) { w0 = w1 = w2 = w3 = 0; x0 = x1 = x2 = x3 = 0; }
        const short8 pf = mk8(w0, w1, w2, w3);
        const short8 pe = mk8(x0, x1, x2, x3);

        // PV: out^T[dt*16 + 4g + r][t], residual-corrected
        float* op = ob + (size_t)(ti * 16 + t) * CDIM + 4 * g;
        #pragma unroll
        for (int dt = 0; dt < 4; ++dt) {
            floatx4 od = {0.f, 0.f, 0.f, 0.f};
            od = __builtin_amdgcn_mfma_f32_16x16x32_bf16(avf[dt], pf, od, 0, 0, 0);
            od = __builtin_amdgcn_mfma_f32_16x16x32_bf16(avf[dt], pe, od, 0, 0, 0);
            od = __builtin_amdgcn_mfma_f32_16x16x32_bf16(ave[dt], pf, od, 0, 0, 0);
            *(floatx4*)(op + dt * 16) = od;
        }
    }
}

// ---------- launcher ----------
extern "C" void kernel_launch(void* const* d_in, const int* in_sizes, int n_in,
                              void* d_out, int out_size, void* d_ws, size_t ws_size,
                              hipStream_t stream) {
    (void)in_sizes; (void)n_in; (void)out_size; (void)ws_size;
    const float* s1 = (const float*)d_in[0];
    const float* s2 = (const float*)d_in[1];
    const float* Wq = (const float*)d_in[2];
    const float* bq = (const float*)d_in[3];
    const float* Wk = (const float*)d_in[4];
    const float* bk = (const float*)d_in[5];
    const float* Wv = (const float*)d_in[6];
    const float* bv = (const float*)d_in[7];
    const float* na = (const float*)d_in[9];
    const float* ha = (const float*)d_in[12];
    const float* wa = (const float*)d_in[13];
    float* out = (float*)d_out;

    char* ws = (char*)d_ws;
    ushort_t* q_hm = (ushort_t*)(ws);                 // 50,331,648 B  [96][4096][64]
    ushort_t* k_hm = (ushort_t*)(ws + 50331648);      // 50,331,648 B
    ushort_t* v_hm = (ushort_t*)(ws + 100663296);     // 50,331,648 B
    float* agent   = (float*)(ws + 150994944);        //    393,216 B  [96][16][64]
    float* Sp      = (float*)(ws + 151388160);        //    196,608 B  [96][16][32]  (transposed)
    float* ab      = (float*)(ws + 151584768);        //        768 B
    ushort_t* wb   = (ushort_t*)(ws + 151585536);     //  3,538,944 B  [3][768][768]
    ushort_t* abuf = (ushort_t*)(ws + 155124480);     // 100,663,296 B [2][32768][768]  (live cvt_a..gemm)
    float* avp     = (float*)(ws + 155124480);        // 12,582,912 B  [32][96][16][64] (live stage1..stage2, overlays dead abuf)

    prep     <<<dim3(961),       256, 0, stream>>>(Wq, Wk, Wv, bq, na, ha, wa,
                                                   wb, agent, ab);
    cvt_a    <<<dim3(12288, 2),  256, 0, stream>>>(s1, s2, abuf);
    gemm_qkv <<<dim3(256, 6, 3), 256, 0, stream>>>(abuf, wb, bq, bk, bv,
                                                   q_hm, k_hm, v_hm, agent);
    stage1   <<<dim3(96, 16),    512, 0, stream>>>(k_hm, v_hm, agent, Sp, avp);
    stage2   <<<dim3(16, 96),    256, 0, stream>>>(q_hm, avp, Sp, agent, ab, out);
}

// Round 11
// 264.094 us; speedup vs baseline: 1.1832x; 1.0167x over previous
//
#include <hip/hip_runtime.h>
#include <cstdint>
#include <cstddef>

typedef unsigned short ushort_t;
typedef unsigned int uint;

typedef __attribute__((ext_vector_type(8))) short short8;   // 8 x bf16 (4 VGPRs)
typedef __attribute__((ext_vector_type(4))) float floatx4;  // 4 x f32

#define CDIM 768

// ---------- bf16 helpers (raw ushort representation) ----------
__device__ __forceinline__ float bfu(ushort_t u) {
    return __uint_as_float(((uint)u) << 16);
}
__device__ __forceinline__ void bf2(uint u, float& lo, float& hi) {
    lo = __uint_as_float(u << 16);
    hi = __uint_as_float(u & 0xffff0000u);
}
__device__ __forceinline__ ushort_t f2bfu(float f) {
    uint u = __float_as_uint(f);
    u += 0x7fffu + ((u >> 16) & 1u);   // round-to-nearest-even
    return (ushort_t)(u >> 16);
}
__device__ __forceinline__ uint pack2(float a, float b) {     // RNE pack
    return (uint)f2bfu(a) | ((uint)f2bfu(b) << 16);
}
// packed RNE f32x2 -> bf16x2 (low word = first operand), 1 VALU inst
__device__ __forceinline__ uint cvt2(float lo, float hi) {
    uint r;
    asm("v_cvt_pk_bf16_f32 %0, %1, %2" : "=v"(r) : "v"(lo), "v"(hi));
    return r;
}
__device__ __forceinline__ short8 mk8(uint a, uint b, uint c, uint d) {
    union { uint4 u; short8 s; } x;
    x.u = (uint4){a, b, c, d};
    return x.s;
}
__device__ __forceinline__ void gload_lds16(const void* g, void* l) {
    __builtin_amdgcn_global_load_lds(
        (__attribute__((address_space(1))) void*)(uintptr_t)g,
        (__attribute__((address_space(3))) void*)l, 16, 0, 0);
}

// ---------- Kernel 0: cvt_all = cvt_a (24576 blocks) + cvt_w (864) +
// init_agent (96) + bias_ab (1). prep rides along the GPU-filling cvt grid. --
__global__ __launch_bounds__(256) void cvt_all(
    const float* __restrict__ s1, const float* __restrict__ s2,
    const float* __restrict__ Wq, const float* __restrict__ Wk,
    const float* __restrict__ Wv, const float* __restrict__ bq,
    const float* __restrict__ na, const float* __restrict__ ha,
    const float* __restrict__ wa,
    ushort_t* __restrict__ abuf, ushort_t* __restrict__ wb,
    float* __restrict__ agent, float* __restrict__ ab)
{
    const int bid = blockIdx.x;
    if (bid < 24576) {
        // s1/s2 (fp32) -> bf16 activations
        const int m = (bid >= 12288);
        const int bx = bid - m * 12288;
        const float* src = (m == 0) ? s1 : s2;
        ushort_t* dst = abuf + (size_t)m * 25165824;
        const size_t i = ((size_t)bx * 256 + threadIdx.x) * 8;
        const float4 f0 = *(const float4*)(src + i);
        const float4 f1 = *(const float4*)(src + i + 4);
        uint4 u;
        u.x = pack2(f0.x, f0.y);
        u.y = pack2(f0.z, f0.w);
        u.z = pack2(f1.x, f1.y);
        u.w = pack2(f1.z, f1.w);
        *(uint4*)(dst + i) = u;
    } else if (bid < 25440) {
        // Wq/Wk/Wv (fp32) -> bf16 RNE
        const int wid = bid - 24576;
        const int m = wid / 288;
        const float* src = (m == 0) ? Wq : (m == 1 ? Wk : Wv);
        ushort_t* dst = wb + (size_t)m * 589824;
        const int i = ((wid % 288) * 256 + threadIdx.x) * 8;
        const float4 f0 = *(const float4*)(src + i);
        const float4 f1 = *(const float4*)(src + i + 4);
        uint4 u;
        u.x = pack2(f0.x, f0.y);
        u.y = pack2(f0.z, f0.w);
        u.z = pack2(f1.x, f1.y);
        u.w = pack2(f1.z, f1.w);
        *(uint4*)(dst + i) = u;
    } else if (bid < 25536) {
        // init agent accumulator with the q-bias
        const int bh = bid - 25440;
        const int h = bh % 12;
        for (int i = threadIdx.x; i < 1024; i += 256)
            agent[(size_t)bh * 1024 + i] = bq[h * 64 + (i & 63)];
    } else {
        // stage-2 agent bias ab[h][a]
        const int t = threadIdx.x;
        if (t >= 192) return;
        const int h = t >> 4, a = t & 15;
        const float cw[7] = {2.25f, 2.34375f, 2.28125f, 2.25f, 2.28125f, 2.34375f, 2.25f};
        float acc = 0.f;
        const float* nb = na + (h * 16 + a) * 49;
        for (int i = 0; i < 7; ++i)
            for (int j = 0; j < 7; ++j)
                acc += cw[i] * cw[j] * nb[i * 7 + j];
        acc *= (1.0f / 256.0f);
        float s = 0.f;
        for (int p = 0; p < 16; ++p)
            s += ha[(h * 16 + p) * 16 + a] + wa[(h * 16 + p) * 16 + a];
        ab[t] = acc + s * (1.0f / 16.0f);
    }
}

// ---------- Kernel 1: fused QKV GEMM (round-0 structure: all-bf16, pure
// global_load_lds staging) + XCD swizzle + fused agent pooling + LDS-staged
// coalesced epilogue (verified round 8: WRITE_SIZE at ideal 148,992 KB) ----------
__global__ __launch_bounds__(256, 2) void gemm_qkv(
    const ushort_t* __restrict__ ab, const ushort_t* __restrict__ wb,
    const float* __restrict__ bq, const float* __restrict__ bk, const float* __restrict__ bv,
    ushort_t* __restrict__ qo, ushort_t* __restrict__ ko, ushort_t* __restrict__ vo,
    float* __restrict__ agent)
{
    const int z = blockIdx.z;
    const ushort_t* A     = ab + (size_t)(z != 0) * 25165824;
    const ushort_t* W     = wb + (size_t)z * 589824;
    const float* bias     = (z == 0) ? bq : (z == 1 ? bk : bv);
    ushort_t* out         = (z == 0) ? qo : (z == 1 ? ko : vo);

    __shared__ ushort_t lds[17408];     // 34,816 B: At=[0:8192], Wt=[8192:16384];
    ushort_t* At = lds;                 // epilogue reuses all as [128][136]
    ushort_t* Wt = lds + 8192;

    const int tid  = threadIdx.x;
    const int wave = tid >> 6;
    const int lane = tid & 63;
    const int wm = wave >> 1, wn = wave & 1;

    // XCD-aware swizzle: 1536 blocks/plane, 8 XCDs, 192 blocks/chunk (bijective).
    const int id   = blockIdx.x + (blockIdx.y << 8);   // gridDim.x = 256
    const int id2  = (id & 7) * 192 + (id >> 3);
    const int row0 = (id2 / 6) * 128;   // token rows (b*4096+m)
    const int col0 = (id2 % 6) * 128;   // output channels

    // staging: lane j covers row_off = j>>3, source chunk = (j&7) ^ (j>>3)
    const int sro = lane >> 3;
    const int sch = ((lane & 7) ^ sro) * 8;
    const ushort_t* gaBase = A + (size_t)(row0 + wave * 32 + sro) * CDIM + sch;
    const ushort_t* gwBase = W + (size_t)(col0 + wave * 32 + sro) * CDIM + sch;

    floatx4 acc[4][4];
    #pragma unroll
    for (int i = 0; i < 4; ++i)
        #pragma unroll
        for (int j = 0; j < 4; ++j)
            acc[i][j] = (floatx4){0.f, 0.f, 0.f, 0.f};

    const int q4 = lane >> 4, r16 = lane & 15;

    for (int kt = 0; kt < CDIM; kt += 64) {
        __syncthreads();
        #pragma unroll
        for (int i = 0; i < 4; ++i) {
            gload_lds16(gaBase + (size_t)i * 8 * CDIM + kt, &At[(wave * 32 + i * 8) * 64]);
            gload_lds16(gwBase + (size_t)i * 8 * CDIM + kt, &Wt[(wave * 32 + i * 8) * 64]);
        }
        __syncthreads();
        #pragma unroll
        for (int ks = 0; ks < 2; ++ks) {
            short8 af[4], bfr[4];
            #pragma unroll
            for (int mt = 0; mt < 4; ++mt) {
                const int row = wm * 64 + mt * 16 + r16;
                const int ch  = (ks * 4 + q4) ^ (row & 7);
                af[mt] = *(const short8*)&At[row * 64 + ch * 8];
            }
            #pragma unroll
            for (int nt = 0; nt < 4; ++nt) {
                const int row = wn * 64 + nt * 16 + r16;
                const int ch  = (ks * 4 + q4) ^ (row & 7);
                bfr[nt] = *(const short8*)&Wt[row * 64 + ch * 8];
            }
            #pragma unroll
            for (int mt = 0; mt < 4; ++mt)
                #pragma unroll
                for (int nt = 0; nt < 4; ++nt)
                    acc[mt][nt] = __builtin_amdgcn_mfma_f32_16x16x32_bf16(
                        af[mt], bfr[nt], acc[mt][nt], 0, 0, 0);
        }
    }

    // ---- epilogue: LDS-staged coalesced store + fused pool (z==0) ----
    __syncthreads();    // all LDS reads of the last K-tile complete
    const int b = row0 >> 12;
    const int m_base = row0 & 4095;
    #pragma unroll
    for (int nt = 0; nt < 4; ++nt) {
        const int coll = wn * 64 + nt * 16 + r16;     // col-local 0..127
        const float bb = bias[col0 + coll];
        float psum = 0.f;
        #pragma unroll
        for (int mt = 0; mt < 4; ++mt) {
            const int rowl = wm * 64 + mt * 16 + q4 * 4;
            #pragma unroll
            for (int r = 0; r < 4; ++r) {
                lds[(rowl + r) * 136 + coll] = f2bfu(acc[mt][nt][r] + bb);
                psum += acc[mt][nt][r];
            }
        }
        if (z == 0) {
            psum += __shfl_xor(psum, 16);
            psum += __shfl_xor(psum, 32);
            if (q4 == 0) {
                const int h = (col0 + coll) >> 6, d = (col0 + coll) & 63;
                atomicAdd(&agent[(size_t)(b * 12 + h) * 1024 + (m_base >> 8) * 64 + d],
                          psum * (1.0f / 256.0f));
            }
        }
    }
    __syncthreads();
    // 256 rows (128 m x 2 heads) x 128 B; 8 lanes per row, uint4 each.
    #pragma unroll
    for (int it = 0; it < 8; ++it) {
        const int task  = it * 256 + tid;
        const int chunk = task & 7;          // 16-B chunk within the row
        const int rh    = task >> 3;         // 0..255
        const int rowl  = rh >> 1, hl = rh & 1;
        const uint4 v = *(const uint4*)&lds[rowl * 136 + hl * 64 + chunk * 8];
        ushort_t* op = out + ((size_t)(b * 12 + (col0 >> 6) + hl) * 4096
                              + m_base + rowl) * 64 + chunk * 8;
        *(uint4*)op = v;
    }
}

// ---------- Kernel 4: stage 1 (agent -> keys/values), MFMA scores, z-split x16 --
// Part A (MFMA, verified round 9): S^T[a][tok] = mfma(A=ah(value+residual),
// B=K-rows); exp + pack2 -> 8-B E2 store per lane.
// Part B (vectorized, verified round 10): lane covers a d-pair; 2-way m split;
// shfl_xor(32) combine; float2 stores. Sp transposed [bh][a][z2].
__global__ __launch_bounds__(512) void stage1(
    const ushort_t* __restrict__ k_hm, const ushort_t* __restrict__ v_hm,
    const float* __restrict__ agent, float* __restrict__ Sp, float* __restrict__ avp)
{
    const int bh = blockIdx.x, z = blockIdx.y;   // z in [0,16)
    const int tid = threadIdx.x;
    const int lane = tid & 63;
    const int w = tid >> 6;              // wave 0..7
    const int g = lane >> 4;             // quad group 0..3
    const int t = lane & 15;
    __shared__ ushort_t E2[256 * 20];    // [m_local][a] bf16, rows padded to 40 B

    // ah A-fragments (value + residual), scale 0.125 — identical to stage2's
    short8 ahA[2], ahE[2];
    #pragma unroll
    for (int k0 = 0; k0 < 2; ++k0) {
        const float* p = agent + (size_t)bh * 1024 + t * 64 + k0 * 32 + g * 8;
        const float4 f0 = *(const float4*)p;
        const float4 f1 = *(const float4*)(p + 4);
        const float v[8] = {f0.x, f0.y, f0.z, f0.w, f1.x, f1.y, f1.z, f1.w};
        uint u[4], e[4];
        #pragma unroll
        for (int j = 0; j < 4; ++j) {
            const float a0 = v[2*j] * 0.125f, a1 = v[2*j+1] * 0.125f;
            u[j] = cvt2(a0, a1);
            float b0, b1; bf2(u[j], b0, b1);
            e[j] = cvt2(a0 - b0, a1 - b1);
        }
        ahA[k0] = mk8(u[0], u[1], u[2], u[3]);
        ahE[k0] = mk8(e[0], e[1], e[2], e[3]);
    }

    const int m0 = z * 256;
    const ushort_t* kb = k_hm + ((size_t)bh * 4096 + m0) * 64;

    #pragma unroll
    for (int ti = 0; ti < 2; ++ti) {
        const int row = w * 32 + ti * 16 + t;
        const ushort_t* kp = kb + (size_t)row * 64 + g * 8;
        const short8 kB0 = *(const short8*)(kp);
        const short8 kB1 = *(const short8*)(kp + 32);
        floatx4 sc = {0.f, 0.f, 0.f, 0.f};
        sc = __builtin_amdgcn_mfma_f32_16x16x32_bf16(ahA[0], kB0, sc, 0, 0, 0);
        sc = __builtin_amdgcn_mfma_f32_16x16x32_bf16(ahA[1], kB1, sc, 0, 0, 0);
        sc = __builtin_amdgcn_mfma_f32_16x16x32_bf16(ahE[0], kB0, sc, 0, 0, 0);
        sc = __builtin_amdgcn_mfma_f32_16x16x32_bf16(ahE[1], kB1, sc, 0, 0, 0);
        const uint P0 = pack2(__expf(sc[0]), __expf(sc[1]));
        const uint P1 = pack2(__expf(sc[2]), __expf(sc[3]));
        *(uint2*)&E2[(size_t)row * 20 + g * 4] = make_uint2(P0, P1);
    }
    __syncthreads();

    // part B: quad gg of agents, half of m (128 rows), mseg splits it 2x64;
    // lane ls covers d-pair (d0, d0+1).
    const int gg = (tid >> 6) & 3;
    const int half = tid >> 8;           // 0/1
    const int ls = lane & 31;
    const int mseg = lane >> 5;          // 0/1
    const int d0 = ls * 2;
    const int mb = half * 128 + mseg * 64;
    const ushort_t* vb = v_hm + ((size_t)bh * 4096 + m0 + mb) * 64 + d0;
    float ac[4][2];
    float ss[4];
    #pragma unroll
    for (int a = 0; a < 4; ++a) { ac[a][0] = 0.f; ac[a][1] = 0.f; ss[a] = 0.f; }
    for (int ml = 0; ml < 64; ++ml) {
        const uint vv = *(const uint*)(vb + (size_t)ml * 64);
        float v0, v1;
        bf2(vv, v0, v1);
        const uint2 ee = *(const uint2*)&E2[(size_t)(mb + ml) * 20 + gg * 4];
        float e0, e1, e2, e3;
        bf2(ee.x, e0, e1);
        bf2(ee.y, e2, e3);
        ac[0][0] += e0 * v0; ac[0][1] += e0 * v1; ss[0] += e0;
        ac[1][0] += e1 * v0; ac[1][1] += e1 * v1; ss[1] += e1;
        ac[2][0] += e2 * v0; ac[2][1] += e2 * v1; ss[2] += e2;
        ac[3][0] += e3 * v0; ac[3][1] += e3 * v1; ss[3] += e3;
    }
    #pragma unroll
    for (int a = 0; a < 4; ++a) {
        ac[a][0] += __shfl_xor(ac[a][0], 32);
        ac[a][1] += __shfl_xor(ac[a][1], 32);
        ss[a]    += __shfl_xor(ss[a], 32);
    }
    const int z2 = z * 2 + half;         // 0..31
    if (mseg == 0) {
        float* avz = avp + (size_t)(z2 * 96 + bh) * 1024;
        #pragma unroll
        for (int a = 0; a < 4; ++a)
            *(float2*)&avz[(gg * 4 + a) * 64 + d0] = make_float2(ac[a][0], ac[a][1]);
        if (ls == 0) {
            #pragma unroll
            for (int a = 0; a < 4; ++a)
                Sp[((size_t)bh * 16 + gg * 4 + a) * 32 + z2] = ss[a];
        }
    }
}

// ---------- Kernel 4b: reduce partials -> normalized agent_v (once per bh) ----
// Byte-identical arithmetic to stage2's former prologue -> bitwise-same avn.
// Removes the 16x redundant avp re-read (201 MB -> 12.6 MB).
__global__ __launch_bounds__(256) void redu(
    const float* __restrict__ avp, const float* __restrict__ Sp,
    float* __restrict__ avn_g)
{
    const int bh = blockIdx.x;
    const int tid = threadIdx.x;
    const int i4 = tid * 4;
    const int a = i4 >> 6;
    floatx4 num = {0.f, 0.f, 0.f, 0.f};
    #pragma unroll
    for (int zz = 0; zz < 32; ++zz)
        num += *(const floatx4*)&avp[(size_t)(zz * 96 + bh) * 1024 + i4];
    const float* sp = Sp + ((size_t)bh * 16 + a) * 32;
    floatx4 dv = {0.f, 0.f, 0.f, 0.f};
    #pragma unroll
    for (int j = 0; j < 8; ++j)
        dv += *(const floatx4*)(sp + j * 4);
    const float r = 1.0f / (dv[0] + dv[1] + dv[2] + dv[3]);
    *(floatx4*)&avn_g[(size_t)bh * 1024 + i4] = num * r;
}

// ---------- Kernel 5: stage 2 (queries -> agents) via MFMA ----------
// Swapped-operand scheme (verified round 5). avn pre-reduced by redu.
__global__ __launch_bounds__(256) void stage2(
    const ushort_t* __restrict__ q_hm, const float* __restrict__ avn_g,
    const float* __restrict__ agent, const float* __restrict__ ab,
    float* __restrict__ out)
{
    const int nb = blockIdx.x;           // 16
    const int bh = blockIdx.y;           // 96
    const int b = bh / 12, h = bh % 12;
    const int tid = threadIdx.x;
    const int g = (tid >> 4) & 3;        // lane>>4 (quad group)
    const int t = tid & 15;              // lane&15
    const int w = tid >> 6;              // wave
    __shared__ float avn[1024];          // normalized agent_v, [a][d] fp32

    {
        const int i4 = tid * 4;
        *(floatx4*)&avn[i4] = *(const floatx4*)&avn_g[(size_t)bh * 1024 + i4];
    }
    __syncthreads();

    // ah A-fragments (value + residual): lane holds ah[t][k0*32 + g*8 + j]*scale
    short8 ahA[2], ahE[2];
    #pragma unroll
    for (int k0 = 0; k0 < 2; ++k0) {
        const float* p = agent + (size_t)bh * 1024 + t * 64 + k0 * 32 + g * 8;
        const float4 f0 = *(const float4*)p;
        const float4 f1 = *(const float4*)(p + 4);
        const float v[8] = {f0.x, f0.y, f0.z, f0.w, f1.x, f1.y, f1.z, f1.w};
        uint u[4], e[4];
        #pragma unroll
        for (int j = 0; j < 4; ++j) {
            const float a0 = v[2*j] * 0.125f, a1 = v[2*j+1] * 0.125f;
            u[j] = cvt2(a0, a1);
            float b0, b1; bf2(u[j], b0, b1);
            e[j] = cvt2(a0 - b0, a1 - b1);
        }
        ahA[k0] = mk8(u[0], u[1], u[2], u[3]);
        ahE[k0] = mk8(e[0], e[1], e[2], e[3]);
    }

    // av^T A-fragments (value + residual): lane holds avn[8g+j][dt*16 + t]; g>=2 zero
    short8 avf[4], ave[4];
    #pragma unroll
    for (int dt = 0; dt < 4; ++dt) {
        uint u[4] = {0, 0, 0, 0}, e[4] = {0, 0, 0, 0};
        if (g < 2) {
            #pragma unroll
            for (int j = 0; j < 4; ++j) {
                const float a0 = avn[(8*g + 2*j)     * 64 + dt * 16 + t];
                const float a1 = avn[(8*g + 2*j + 1) * 64 + dt * 16 + t];
                u[j] = cvt2(a0, a1);
                float b0, b1; bf2(u[j], b0, b1);
                e[j] = cvt2(a0 - b0, a1 - b1);
            }
        }
        avf[dt] = mk8(u[0], u[1], u[2], u[3]);
        ave[dt] = mk8(e[0], e[1], e[2], e[3]);
    }

    float abv[4];
    #pragma unroll
    for (int r = 0; r < 4; ++r) abv[r] = ab[h * 16 + 4 * g + r];

    const int src0 = (t + 32 * g) & 63;
    const int src1 = (src0 + 16) & 63;
    const int n0 = nb * 256 + w * 64;
    const ushort_t* qb = q_hm + ((size_t)bh * 4096 + n0) * 64;
    float* ob = out + ((size_t)b * 4096 + n0) * CDIM + h * 64;

    #pragma unroll
    for (int ti = 0; ti < 4; ++ti) {
        // Q B-fragments: lane holds Q[ti*16+t][k0*32 + g*8 + j]
        const ushort_t* qp = qb + (size_t)(ti * 16 + t) * 64 + g * 8;
        const short8 qB0 = *(const short8*)(qp);
        const short8 qB1 = *(const short8*)(qp + 32);

        floatx4 sc = {0.f, 0.f, 0.f, 0.f};
        sc = __builtin_amdgcn_mfma_f32_16x16x32_bf16(ahA[0], qB0, sc, 0, 0, 0);
        sc = __builtin_amdgcn_mfma_f32_16x16x32_bf16(ahA[1], qB1, sc, 0, 0, 0);
        sc = __builtin_amdgcn_mfma_f32_16x16x32_bf16(ahE[0], qB0, sc, 0, 0, 0);
        sc = __builtin_amdgcn_mfma_f32_16x16x32_bf16(ahE[1], qB1, sc, 0, 0, 0);

        // softmax over agents (rows): in-lane + cross-group
        const float e0 = __expf(sc[0] + abv[0]);
        const float e1 = __expf(sc[1] + abv[1]);
        const float e2 = __expf(sc[2] + abv[2]);
        const float e3 = __expf(sc[3] + abv[3]);
        float s = e0 + e1 + e2 + e3;
        s += __shfl_xor(s, 16);
        s += __shfl_xor(s, 32);
        const float rs = 1.0f / s;
        const float p0 = e0 * rs, p1 = e1 * rs, p2 = e2 * rs, p3 = e3 * rs;

        // pack own P (agents 4g..4g+3, token t) + residual
        const uint P0 = cvt2(p0, p1), P1 = cvt2(p2, p3);
        float q0, q1, q2, q3;
        bf2(P0, q0, q1); bf2(P1, q2, q3);
        const uint E0 = cvt2(p0 - q0, p1 - q1), E1 = cvt2(p2 - q2, p3 - q3);

        // regroup into K=32-padded B-fragment: k=8g+j -> agents from groups 2g, 2g+1
        uint w0 = __shfl(P0, src0), w1 = __shfl(P1, src0);
        uint w2 = __shfl(P0, src1), w3 = __shfl(P1, src1);
        uint x0 = __shfl(E0, src0), x1 = __shfl(E1, src0);
        uint x2 = __shfl(E0, src1), x3 = __shfl(E1, src1);
        if (g >= 2) { w0 = w1 = w2 = w3 = 0; x0 = x1 = x2 = x3 = 0; }
        const short8 pf = mk8(w0, w1, w2, w3);
        const short8 pe = mk8(x0, x1, x2, x3);

        // PV: out^T[dt*16 + 4g + r][t], residual-corrected
        float* op = ob + (size_t)(ti * 16 + t) * CDIM + 4 * g;
        #pragma unroll
        for (int dt = 0; dt < 4; ++dt) {
            floatx4 od = {0.f, 0.f, 0.f, 0.f};
            od = __builtin_amdgcn_mfma_f32_16x16x32_bf16(avf[dt], pf, od, 0, 0, 0);
            od = __builtin_amdgcn_mfma_f32_16x16x32_bf16(avf[dt], pe, od, 0, 0, 0);
            od = __builtin_amdgcn_mfma_f32_16x16x32_bf16(ave[dt], pf, od, 0, 0, 0);
            *(floatx4*)(op + dt * 16) = od;
        }
    }
}

// ---------- launcher ----------
extern "C" void kernel_launch(void* const* d_in, const int* in_sizes, int n_in,
                              void* d_out, int out_size, void* d_ws, size_t ws_size,
                              hipStream_t stream) {
    (void)in_sizes; (void)n_in; (void)out_size; (void)ws_size;
    const float* s1 = (const float*)d_in[0];
    const float* s2 = (const float*)d_in[1];
    const float* Wq = (const float*)d_in[2];
    const float* bq = (const float*)d_in[3];
    const float* Wk = (const float*)d_in[4];
    const float* bk = (const float*)d_in[5];
    const float* Wv = (const float*)d_in[6];
    const float* bv = (const float*)d_in[7];
    const float* na = (const float*)d_in[9];
    const float* ha = (const float*)d_in[12];
    const float* wa = (const float*)d_in[13];
    float* out = (float*)d_out;

    char* ws = (char*)d_ws;
    ushort_t* q_hm = (ushort_t*)(ws);                 // 50,331,648 B  [96][4096][64]
    ushort_t* k_hm = (ushort_t*)(ws + 50331648);      // 50,331,648 B
    ushort_t* v_hm = (ushort_t*)(ws + 100663296);     // 50,331,648 B
    float* agent   = (float*)(ws + 150994944);        //    393,216 B  [96][16][64]
    float* Sp      = (float*)(ws + 151388160);        //    196,608 B  [96][16][32]  (transposed)
    float* ab      = (float*)(ws + 151584768);        //        768 B
    float* avn_g   = (float*)(ws + 151585536);        //    393,216 B  [96][16][64]
    ushort_t* wb   = (ushort_t*)(ws + 151978752);     //  3,538,944 B  [3][768][768]
    ushort_t* abuf = (ushort_t*)(ws + 155517696);     // 100,663,296 B [2][32768][768]  (live cvt..gemm)
    float* avp     = (float*)(ws + 155517696);        // 12,582,912 B  [32][96][16][64] (live stage1..redu, overlays dead abuf)

    cvt_all  <<<dim3(25537),     256, 0, stream>>>(s1, s2, Wq, Wk, Wv, bq,
                                                   na, ha, wa, abuf, wb, agent, ab);
    gemm_qkv <<<dim3(256, 6, 3), 256, 0, stream>>>(abuf, wb, bq, bk, bv,
                                                   q_hm, k_hm, v_hm, agent);
    stage1   <<<dim3(96, 16),    512, 0, stream>>>(k_hm, v_hm, agent, Sp, avp);
    redu     <<<dim3(96),        256, 0, stream>>>(avp, Sp, avn_g);
    stage2   <<<dim3(16, 96),    256, 0, stream>>>(q_hm, avn_g, agent, ab, out);
}